// Round 1
// baseline (2260.227 us; speedup 1.0000x reference)
//
#include <hip/hip_runtime.h>

#define SS 336
#define VV 8
#define DD 256
#define DKK 32
#define NTOK 5376            // B*V*S = B*S*V tokens
#define NTD (NTOK * DD)      // 1376256 floats per activation buffer
#define ATT_SCALE 0.17677669529663687f  // 1/sqrt(32)
#define LN_EPS 1e-5f

// ---------------- embed: E_time[(b*V+v)*S+s][d] = x[b,s,v]*ew[d]+eb[d] ----
__global__ __launch_bounds__(256) void k_embed(
    const float* __restrict__ x, const float* __restrict__ ew,
    const float* __restrict__ eb, float* __restrict__ E) {
  int token = blockIdx.x;            // (b*V+v)*S + s
  int n = token / SS, s = token - n * SS;
  int b = n >> 3, v = n & 7;
  float xv = x[(b * SS + s) * VV + v];
  int d = threadIdx.x;
  E[token * DD + d] = fmaf(xv, ew[d], eb[d]);
}

// ---------------- 64x64-tile fp32 GEMM: Y = A[5376,256] @ W[256,256] + bias
// grid (84, 4, z); z selects among up to 3 weight/bias/output triples.
// Optional residual add (Res != nullptr).
__global__ __launch_bounds__(256) void k_gemm(
    const float* __restrict__ A,
    const float* __restrict__ W0, const float* __restrict__ W1,
    const float* __restrict__ W2,
    const float* __restrict__ c0, const float* __restrict__ c1,
    const float* __restrict__ c2,
    float* __restrict__ Y0, float* __restrict__ Y1, float* __restrict__ Y2,
    const float* __restrict__ Res) {
  int z = blockIdx.z;
  const float* W    = (z == 0) ? W0 : (z == 1) ? W1 : W2;
  const float* bias = (z == 0) ? c0 : (z == 1) ? c1 : c2;
  float* Y          = (z == 0) ? Y0 : (z == 1) ? Y1 : Y2;
  int m0 = blockIdx.x * 64, n0 = blockIdx.y * 64;
  __shared__ float As[16][68];   // As[k][m] (transposed), pad 68 keeps 16B align
  __shared__ float Wt[16][68];   // Wt[k][n]
  int tid = threadIdx.x;
  int tx = tid & 15, ty = tid >> 4;
  int arow = tid >> 2, akq = tid & 3;   // A tile loader: row 0..63, k-quad 0..3
  int wk = tid >> 4, wn = tid & 15;     // W tile loader: k 0..15, n-quad 0..15
  float acc[4][4] = {{0.f, 0.f, 0.f, 0.f}, {0.f, 0.f, 0.f, 0.f},
                     {0.f, 0.f, 0.f, 0.f}, {0.f, 0.f, 0.f, 0.f}};
  for (int k0 = 0; k0 < 256; k0 += 16) {
    __syncthreads();
    float4 a = *(const float4*)&A[(m0 + arow) * 256 + k0 + 4 * akq];
    As[4 * akq + 0][arow] = a.x;
    As[4 * akq + 1][arow] = a.y;
    As[4 * akq + 2][arow] = a.z;
    As[4 * akq + 3][arow] = a.w;
    *(float4*)&Wt[wk][4 * wn] = *(const float4*)&W[(k0 + wk) * 256 + n0 + 4 * wn];
    __syncthreads();
#pragma unroll
    for (int k = 0; k < 16; ++k) {
      float4 av = *(const float4*)&As[k][4 * ty];
      float4 wv = *(const float4*)&Wt[k][4 * tx];
      acc[0][0] = fmaf(av.x, wv.x, acc[0][0]);
      acc[0][1] = fmaf(av.x, wv.y, acc[0][1]);
      acc[0][2] = fmaf(av.x, wv.z, acc[0][2]);
      acc[0][3] = fmaf(av.x, wv.w, acc[0][3]);
      acc[1][0] = fmaf(av.y, wv.x, acc[1][0]);
      acc[1][1] = fmaf(av.y, wv.y, acc[1][1]);
      acc[1][2] = fmaf(av.y, wv.z, acc[1][2]);
      acc[1][3] = fmaf(av.y, wv.w, acc[1][3]);
      acc[2][0] = fmaf(av.z, wv.x, acc[2][0]);
      acc[2][1] = fmaf(av.z, wv.y, acc[2][1]);
      acc[2][2] = fmaf(av.z, wv.z, acc[2][2]);
      acc[2][3] = fmaf(av.z, wv.w, acc[2][3]);
      acc[3][0] = fmaf(av.w, wv.x, acc[3][0]);
      acc[3][1] = fmaf(av.w, wv.y, acc[3][1]);
      acc[3][2] = fmaf(av.w, wv.z, acc[3][2]);
      acc[3][3] = fmaf(av.w, wv.w, acc[3][3]);
    }
  }
  float4 bb4 = *(const float4*)&bias[n0 + 4 * tx];
#pragma unroll
  for (int i = 0; i < 4; ++i) {
    int r = m0 + 4 * ty + i;
    float4 o;
    o.x = acc[i][0] + bb4.x;
    o.y = acc[i][1] + bb4.y;
    o.z = acc[i][2] + bb4.z;
    o.w = acc[i][3] + bb4.w;
    if (Res) {
      float4 rr = *(const float4*)&Res[r * 256 + n0 + 4 * tx];
      o.x += rr.x; o.y += rr.y; o.z += rr.z; o.w += rr.w;
    }
    *(float4*)&Y[r * 256 + n0 + 4 * tx] = o;
  }
}

// ---------------- time attention: N=16, L=336, per-wave 56 q-rows ----------
// grid (6 chunks, 8 heads, 16 n), block 64 (56 active q-rows)
__global__ __launch_bounds__(64) void k_attn_time(
    const float* __restrict__ Q, const float* __restrict__ K,
    const float* __restrict__ V, float* __restrict__ O) {
  int chunk = blockIdx.x, h = blockIdx.y, n = blockIdx.z;
  int tid = threadIdx.x;
  __shared__ float Ks[112 * 32];
  __shared__ float Vs[112 * 32];
  int qr = chunk * 56 + tid;
  bool act = (tid < 56);
  float4 q4[8], o4[8];
  if (act) {
    const float4* qp = (const float4*)&Q[(n * SS + qr) * DD + h * DKK];
#pragma unroll
    for (int j = 0; j < 8; ++j) q4[j] = qp[j];
  }
#pragma unroll
  for (int j = 0; j < 8; ++j) o4[j] = make_float4(0.f, 0.f, 0.f, 0.f);
  float m = -1e30f, l = 0.f;
  for (int kt = 0; kt < 3; ++kt) {
    __syncthreads();
    for (int f = tid; f < 896; f += 64) {   // 112 rows * 8 float4
      int row = f >> 3, j = f & 7;
      const float4* kp = (const float4*)&K[(n * SS + kt * 112 + row) * DD + h * DKK];
      ((float4*)Ks)[f] = kp[j];
      const float4* vp = (const float4*)&V[(n * SS + kt * 112 + row) * DD + h * DKK];
      ((float4*)Vs)[f] = vp[j];
    }
    __syncthreads();
    if (act) {
      for (int kk = 0; kk < 112; ++kk) {
        const float4* krow = (const float4*)&Ks[kk * 32];
        float s0 = 0.f, s1 = 0.f, s2 = 0.f, s3 = 0.f;
#pragma unroll
        for (int j = 0; j < 8; ++j) {
          float4 kv = krow[j];
          s0 = fmaf(q4[j].x, kv.x, s0);
          s1 = fmaf(q4[j].y, kv.y, s1);
          s2 = fmaf(q4[j].z, kv.z, s2);
          s3 = fmaf(q4[j].w, kv.w, s3);
        }
        float s = ((s0 + s1) + (s2 + s3)) * ATT_SCALE;
        float mn = fmaxf(m, s);
        float corr = __expf(m - mn);
        float p = __expf(s - mn);
        l = fmaf(l, corr, p);
        const float4* vrow = (const float4*)&Vs[kk * 32];
#pragma unroll
        for (int j = 0; j < 8; ++j) {
          float4 vv = vrow[j];
          o4[j].x = fmaf(o4[j].x, corr, p * vv.x);
          o4[j].y = fmaf(o4[j].y, corr, p * vv.y);
          o4[j].z = fmaf(o4[j].z, corr, p * vv.z);
          o4[j].w = fmaf(o4[j].w, corr, p * vv.w);
        }
        m = mn;
      }
    }
  }
  if (act) {
    float inv = 1.f / l;
    float4* op = (float4*)&O[(n * SS + qr) * DD + h * DKK];
#pragma unroll
    for (int j = 0; j < 8; ++j) {
      float4 o;
      o.x = o4[j].x * inv; o.y = o4[j].y * inv;
      o.z = o4[j].z * inv; o.w = o4[j].w * inv;
      op[j] = o;
    }
  }
}

// ---------------- variable attention: N=672, L=8, one block per n ---------
// block 64 = (h 0..7) x (qi 0..7). LDS layout [h][k][32] with stride 260
// so the 8 h-groups land on disjoint banks.
__global__ __launch_bounds__(64) void k_attn_var(
    const float* __restrict__ Q, const float* __restrict__ K,
    const float* __restrict__ V, float* __restrict__ O) {
  int n = blockIdx.x;
  int tid = threadIdx.x;
  __shared__ float Ks[2080];
  __shared__ float Vs[2080];
  for (int f = tid; f < 512; f += 64) {   // 8 rows * 64 float4
    int l = f >> 6, c4 = f & 63, h = c4 >> 3, j = c4 & 7;
    float4 kv = ((const float4*)K)[(n * VV + l) * 64 + c4];
    *(float4*)&Ks[h * 260 + l * 32 + 4 * j] = kv;
    float4 vv = ((const float4*)V)[(n * VV + l) * 64 + c4];
    *(float4*)&Vs[h * 260 + l * 32 + 4 * j] = vv;
  }
  __syncthreads();
  int h = tid >> 3, qi = tid & 7;
  float4 q4[8];
  const float4* qp = (const float4*)&Q[(n * VV + qi) * DD + h * DKK];
#pragma unroll
  for (int j = 0; j < 8; ++j) q4[j] = qp[j];
  float sc[8];
#pragma unroll
  for (int k = 0; k < 8; ++k) {
    const float4* krow = (const float4*)&Ks[h * 260 + k * 32];
    float s0 = 0.f, s1 = 0.f, s2 = 0.f, s3 = 0.f;
#pragma unroll
    for (int j = 0; j < 8; ++j) {
      float4 kv = krow[j];
      s0 = fmaf(q4[j].x, kv.x, s0);
      s1 = fmaf(q4[j].y, kv.y, s1);
      s2 = fmaf(q4[j].z, kv.z, s2);
      s3 = fmaf(q4[j].w, kv.w, s3);
    }
    sc[k] = ((s0 + s1) + (s2 + s3)) * ATT_SCALE;
  }
  float mx = sc[0];
#pragma unroll
  for (int k = 1; k < 8; ++k) mx = fmaxf(mx, sc[k]);
  float psum = 0.f;
#pragma unroll
  for (int k = 0; k < 8; ++k) {
    sc[k] = __expf(sc[k] - mx);
    psum += sc[k];
  }
  float inv = 1.f / psum;
  float4* op = (float4*)&O[(n * VV + qi) * DD + h * DKK];
#pragma unroll
  for (int j = 0; j < 8; ++j) {
    float ax = 0.f, ay = 0.f, az = 0.f, aw = 0.f;
#pragma unroll
    for (int k = 0; k < 8; ++k) {
      float4 vv = *(const float4*)&Vs[h * 260 + k * 32 + 4 * j];
      ax = fmaf(sc[k], vv.x, ax);
      ay = fmaf(sc[k], vv.y, ay);
      az = fmaf(sc[k], vv.z, az);
      aw = fmaf(sc[k], vv.w, aw);
    }
    float4 o;
    o.x = ax * inv; o.y = ay * inv; o.z = az * inv; o.w = aw * inv;
    op[j] = o;
  }
}

// ---------------- LN helpers: one wave per token row ------------------------
// double LN (ln1 then norm), input rows in time layout, output permuted to var
__global__ __launch_bounds__(256) void k_ln_double(
    const float* __restrict__ T, const float* __restrict__ g1,
    const float* __restrict__ c1, const float* __restrict__ g2,
    const float* __restrict__ c2, float* __restrict__ Ev) {
  int r = blockIdx.x * 4 + (threadIdx.x >> 6);
  int lane = threadIdx.x & 63;
  float4 xv = ((const float4*)T)[r * 64 + lane];
  float sum = xv.x + xv.y + xv.z + xv.w;
  float sq = fmaf(xv.x, xv.x, fmaf(xv.y, xv.y, fmaf(xv.z, xv.z, xv.w * xv.w)));
#pragma unroll
  for (int off = 32; off > 0; off >>= 1) {
    sum += __shfl_xor(sum, off);
    sq += __shfl_xor(sq, off);
  }
  float mean = sum * (1.0f / 256.0f);
  float var = sq * (1.0f / 256.0f) - mean * mean;
  float rstd = rsqrtf(var + LN_EPS);
  float4 gg = ((const float4*)g1)[lane];
  float4 bb = ((const float4*)c1)[lane];
  float4 z;
  z.x = fmaf((xv.x - mean) * rstd, gg.x, bb.x);
  z.y = fmaf((xv.y - mean) * rstd, gg.y, bb.y);
  z.z = fmaf((xv.z - mean) * rstd, gg.z, bb.z);
  z.w = fmaf((xv.w - mean) * rstd, gg.w, bb.w);
  float sum2 = z.x + z.y + z.z + z.w;
  float sq2 = fmaf(z.x, z.x, fmaf(z.y, z.y, fmaf(z.z, z.z, z.w * z.w)));
#pragma unroll
  for (int off = 32; off > 0; off >>= 1) {
    sum2 += __shfl_xor(sum2, off);
    sq2 += __shfl_xor(sq2, off);
  }
  float mean2 = sum2 * (1.0f / 256.0f);
  float var2 = sq2 * (1.0f / 256.0f) - mean2 * mean2;
  float rstd2 = rsqrtf(var2 + LN_EPS);
  float4 g2v = ((const float4*)g2)[lane];
  float4 b2v = ((const float4*)c2)[lane];
  float4 w;
  w.x = fmaf((z.x - mean2) * rstd2, g2v.x, b2v.x);
  w.y = fmaf((z.y - mean2) * rstd2, g2v.y, b2v.y);
  w.z = fmaf((z.z - mean2) * rstd2, g2v.z, b2v.z);
  w.w = fmaf((z.w - mean2) * rstd2, g2v.w, b2v.w);
  // r = (b*V+v)*S + s  ->  r2 = (b*S+s)*V + v
  int n = r / SS;
  int sidx = r - n * SS;
  int b = n >> 3, v = n & 7;
  int r2 = (b * SS + sidx) * VV + v;
  ((float4*)Ev)[r2 * 64 + lane] = w;
}

// single LN (ln1), input rows in var layout, output permuted back to time
__global__ __launch_bounds__(256) void k_ln_single(
    const float* __restrict__ T, const float* __restrict__ g1,
    const float* __restrict__ c1, float* __restrict__ Et) {
  int r = blockIdx.x * 4 + (threadIdx.x >> 6);
  int lane = threadIdx.x & 63;
  float4 xv = ((const float4*)T)[r * 64 + lane];
  float sum = xv.x + xv.y + xv.z + xv.w;
  float sq = fmaf(xv.x, xv.x, fmaf(xv.y, xv.y, fmaf(xv.z, xv.z, xv.w * xv.w)));
#pragma unroll
  for (int off = 32; off > 0; off >>= 1) {
    sum += __shfl_xor(sum, off);
    sq += __shfl_xor(sq, off);
  }
  float mean = sum * (1.0f / 256.0f);
  float var = sq * (1.0f / 256.0f) - mean * mean;
  float rstd = rsqrtf(var + LN_EPS);
  float4 gg = ((const float4*)g1)[lane];
  float4 bb = ((const float4*)c1)[lane];
  float4 w;
  w.x = fmaf((xv.x - mean) * rstd, gg.x, bb.x);
  w.y = fmaf((xv.y - mean) * rstd, gg.y, bb.y);
  w.z = fmaf((xv.z - mean) * rstd, gg.z, bb.z);
  w.w = fmaf((xv.w - mean) * rstd, gg.w, bb.w);
  // r = (b*S+s)*V + v  ->  r2 = (b*V+v)*S + s
  int t = r >> 3;
  int v = r & 7;
  int b = t / SS;
  int sidx = t - b * SS;
  int r2 = (b * VV + v) * SS + sidx;
  ((float4*)Et)[r2 * 64 + lane] = w;
}

// ---------------- final projection: out[b,p,v] = E[bv,:] . PW[:,p] + PB[p] -
__global__ __launch_bounds__(384) void k_proj_partial(
    const float* __restrict__ E, const float* __restrict__ PW,
    float* __restrict__ Part) {
  int kc = blockIdx.x;            // 128 chunks of 672 k each
  int tid = threadIdx.x;
  int p = tid % 96, g = tid / 96; // 4 k-subgroups
  int kbase = kc * 672 + g * 168;
  float acc[16];
#pragma unroll
  for (int i = 0; i < 16; ++i) acc[i] = 0.f;
  for (int j = 0; j < 168; ++j) {
    int k = kbase + j;
    float w = PW[k * 96 + p];
#pragma unroll
    for (int i = 0; i < 16; ++i) acc[i] = fmaf(E[i * 86016 + k], w, acc[i]);
  }
  __shared__ float sm[16][384];
#pragma unroll
  for (int i = 0; i < 16; ++i) sm[i][tid] = acc[i];
  __syncthreads();
  if (tid < 96) {
#pragma unroll
    for (int i = 0; i < 16; ++i) {
      float ssum = sm[i][tid] + sm[i][96 + tid] + sm[i][192 + tid] + sm[i][288 + tid];
      int b = i >> 3, v = i & 7;
      Part[kc * 1536 + b * 768 + tid * 8 + v] = ssum;
    }
  }
}

__global__ __launch_bounds__(256) void k_proj_reduce(
    const float* __restrict__ Part, const float* __restrict__ PB,
    float* __restrict__ out) {
  int i = blockIdx.x * 256 + threadIdx.x;   // 1536 outputs [b][p][v]
  int p = (i % 768) >> 3;
  float ssum = PB[p];
  for (int c = 0; c < 128; ++c) ssum += Part[c * 1536 + i];
  out[i] = ssum;
}

// ---------------- launch ---------------------------------------------------
extern "C" void kernel_launch(void* const* d_in, const int* in_sizes, int n_in,
                              void* d_out, int out_size, void* d_ws,
                              size_t ws_size, hipStream_t stream) {
  const float* x     = (const float*)d_in[0];
  const float* emb_w = (const float*)d_in[1];
  const float* emb_b = (const float*)d_in[2];
  const float* Wq = (const float*)d_in[3];
  const float* bq = (const float*)d_in[4];
  const float* Wk = (const float*)d_in[5];
  const float* bk = (const float*)d_in[6];
  const float* Wv = (const float*)d_in[7];
  const float* bv = (const float*)d_in[8];
  const float* Wo = (const float*)d_in[9];
  const float* bo = (const float*)d_in[10];
  const float* g1 = (const float*)d_in[11];
  const float* b1 = (const float*)d_in[12];
  const float* gn = (const float*)d_in[13];
  const float* bn = (const float*)d_in[14];
  const float* PW = (const float*)d_in[15];
  const float* PB = (const float*)d_in[16];
  float* out = (float*)d_out;

  float* ws = (float*)d_ws;
  float* Etime = ws;
  float* Evar  = ws + (size_t)NTD;
  float* Qb    = ws + 2 * (size_t)NTD;
  float* Kb    = ws + 3 * (size_t)NTD;
  float* Vb    = ws + 4 * (size_t)NTD;
  float* AO    = ws + 5 * (size_t)NTD;
  float* T1    = ws + 6 * (size_t)NTD;
  float* Part  = ws + 7 * (size_t)NTD;  // 128*1536 floats

  k_embed<<<NTOK, 256, 0, stream>>>(x, emb_w, emb_b, Etime);
  for (int it = 0; it < 10; ++it) {
    // ---- attention over time axis (N=16, L=336) ----
    k_gemm<<<dim3(84, 4, 3), 256, 0, stream>>>(Etime, Wq, Wk, Wv, bq, bk, bv,
                                               Qb, Kb, Vb, nullptr);
    k_attn_time<<<dim3(6, 8, 16), 64, 0, stream>>>(Qb, Kb, Vb, AO);
    k_gemm<<<dim3(84, 4, 1), 256, 0, stream>>>(AO, Wo, Wo, Wo, bo, bo, bo,
                                               T1, T1, T1, Etime);
    k_ln_double<<<NTOK / 4, 256, 0, stream>>>(T1, g1, b1, gn, bn, Evar);
    // ---- attention over variable axis (N=672, L=8) ----
    k_gemm<<<dim3(84, 4, 3), 256, 0, stream>>>(Evar, Wq, Wk, Wv, bq, bk, bv,
                                               Qb, Kb, Vb, nullptr);
    k_attn_var<<<672, 64, 0, stream>>>(Qb, Kb, Vb, AO);
    k_gemm<<<dim3(84, 4, 1), 256, 0, stream>>>(AO, Wo, Wo, Wo, bo, bo, bo,
                                               T1, T1, T1, Evar);
    k_ln_single<<<NTOK / 4, 256, 0, stream>>>(T1, g1, b1, Etime);
  }
  k_proj_partial<<<128, 384, 0, stream>>>(Etime, PW, Part);
  k_proj_reduce<<<6, 256, 0, stream>>>(Part, PB, out);
}

// Round 2
// 2043.897 us; speedup vs baseline: 1.1058x; 1.1058x over previous
//
#include <hip/hip_runtime.h>

#define SS 336
#define VV 8
#define DD 256
#define DKK 32
#define NTOK 5376            // B*V*S = B*S*V tokens
#define NTD (NTOK * DD)      // 1376256 floats per activation buffer
#define ATT_SCALE 0.17677669529663687f  // 1/sqrt(32)
#define LN_EPS 1e-5f

// ---------------- embed: E_time[(b*V+v)*S+s][d] = x[b,s,v]*ew[d]+eb[d] ----
__global__ __launch_bounds__(256) void k_embed(
    const float* __restrict__ x, const float* __restrict__ ew,
    const float* __restrict__ eb, float* __restrict__ E) {
  int token = blockIdx.x;            // (b*V+v)*S + s
  int n = token / SS, s = token - n * SS;
  int b = n >> 3, v = n & 7;
  float xv = x[(b * SS + s) * VV + v];
  int d = threadIdx.x;
  E[token * DD + d] = fmaf(xv, ew[d], eb[d]);
}

// ---------------- 64x64-tile fp32 GEMM: Y = A[5376,256] @ W[256,256] + bias
__global__ __launch_bounds__(256) void k_gemm(
    const float* __restrict__ A,
    const float* __restrict__ W0, const float* __restrict__ W1,
    const float* __restrict__ W2,
    const float* __restrict__ c0, const float* __restrict__ c1,
    const float* __restrict__ c2,
    float* __restrict__ Y0, float* __restrict__ Y1, float* __restrict__ Y2,
    const float* __restrict__ Res) {
  int z = blockIdx.z;
  const float* W    = (z == 0) ? W0 : (z == 1) ? W1 : W2;
  const float* bias = (z == 0) ? c0 : (z == 1) ? c1 : c2;
  float* Y          = (z == 0) ? Y0 : (z == 1) ? Y1 : Y2;
  int m0 = blockIdx.x * 64, n0 = blockIdx.y * 64;
  __shared__ float As[16][68];   // As[k][m] (transposed)
  __shared__ float Wt[16][68];   // Wt[k][n]
  int tid = threadIdx.x;
  int tx = tid & 15, ty = tid >> 4;
  int arow = tid >> 2, akq = tid & 3;
  int wk = tid >> 4, wn = tid & 15;
  float acc[4][4] = {{0.f, 0.f, 0.f, 0.f}, {0.f, 0.f, 0.f, 0.f},
                     {0.f, 0.f, 0.f, 0.f}, {0.f, 0.f, 0.f, 0.f}};
  for (int k0 = 0; k0 < 256; k0 += 16) {
    __syncthreads();
    float4 a = *(const float4*)&A[(m0 + arow) * 256 + k0 + 4 * akq];
    As[4 * akq + 0][arow] = a.x;
    As[4 * akq + 1][arow] = a.y;
    As[4 * akq + 2][arow] = a.z;
    As[4 * akq + 3][arow] = a.w;
    *(float4*)&Wt[wk][4 * wn] = *(const float4*)&W[(k0 + wk) * 256 + n0 + 4 * wn];
    __syncthreads();
#pragma unroll
    for (int k = 0; k < 16; ++k) {
      float4 av = *(const float4*)&As[k][4 * ty];
      float4 wv = *(const float4*)&Wt[k][4 * tx];
      acc[0][0] = fmaf(av.x, wv.x, acc[0][0]);
      acc[0][1] = fmaf(av.x, wv.y, acc[0][1]);
      acc[0][2] = fmaf(av.x, wv.z, acc[0][2]);
      acc[0][3] = fmaf(av.x, wv.w, acc[0][3]);
      acc[1][0] = fmaf(av.y, wv.x, acc[1][0]);
      acc[1][1] = fmaf(av.y, wv.y, acc[1][1]);
      acc[1][2] = fmaf(av.y, wv.z, acc[1][2]);
      acc[1][3] = fmaf(av.y, wv.w, acc[1][3]);
      acc[2][0] = fmaf(av.z, wv.x, acc[2][0]);
      acc[2][1] = fmaf(av.z, wv.y, acc[2][1]);
      acc[2][2] = fmaf(av.z, wv.z, acc[2][2]);
      acc[2][3] = fmaf(av.z, wv.w, acc[2][3]);
      acc[3][0] = fmaf(av.w, wv.x, acc[3][0]);
      acc[3][1] = fmaf(av.w, wv.y, acc[3][1]);
      acc[3][2] = fmaf(av.w, wv.z, acc[3][2]);
      acc[3][3] = fmaf(av.w, wv.w, acc[3][3]);
    }
  }
  float4 bb4 = *(const float4*)&bias[n0 + 4 * tx];
#pragma unroll
  for (int i = 0; i < 4; ++i) {
    int r = m0 + 4 * ty + i;
    float4 o;
    o.x = acc[i][0] + bb4.x;
    o.y = acc[i][1] + bb4.y;
    o.z = acc[i][2] + bb4.z;
    o.w = acc[i][3] + bb4.w;
    if (Res) {
      float4 rr = *(const float4*)&Res[r * 256 + n0 + 4 * tx];
      o.x += rr.x; o.y += rr.y; o.z += rr.z; o.w += rr.w;
    }
    *(float4*)&Y[r * 256 + n0 + 4 * tx] = o;
  }
}

// ---------------- time attention (restructured for occupancy) --------------
// grid (6 qc, 8 h, 16 n), block 256 = 4 waves.
// lanes = q rows (56 active); wave w reduces keys [w*84, (w+1)*84);
// K/V rows are wave-uniform loads (no LDS staging); partials merged via LDS.
__global__ __launch_bounds__(256) void k_attn_time(
    const float* __restrict__ Q, const float* __restrict__ K,
    const float* __restrict__ V, float* __restrict__ O) {
  int qc = blockIdx.x, h = blockIdx.y, n = blockIdx.z;
  int tid = threadIdx.x;
  int wave = tid >> 6, lane = tid & 63;
  int wv = __builtin_amdgcn_readfirstlane(wave);  // provably uniform
  bool act = (lane < 56);
  int qr = qc * 56 + lane;

  __shared__ float Pm[4][56];
  __shared__ float Pl[4][56];
  __shared__ float Pc[4][56];
  __shared__ float Po[4][56 * 36];  // stride 36 rotates banks, keeps 16B align

  float4 q4[8];
  float4 o4[8];
  float m = -1e30f, l = 0.f;
#pragma unroll
  for (int j = 0; j < 8; ++j) o4[j] = make_float4(0.f, 0.f, 0.f, 0.f);

  if (act) {
    const float4* qp = (const float4*)&Q[(size_t)(n * SS + qr) * DD + h * DKK];
#pragma unroll
    for (int j = 0; j < 8; ++j) q4[j] = qp[j];
    const float* Kb_ = K + (size_t)(n * SS + wv * 84) * DD + h * DKK;
    const float* Vb_ = V + (size_t)(n * SS + wv * 84) * DD + h * DKK;
    for (int kk = 0; kk < 84; ++kk) {
      const float4* kp = (const float4*)(Kb_ + (size_t)kk * DD);
      const float4* vp = (const float4*)(Vb_ + (size_t)kk * DD);
      float4 kv[8];
#pragma unroll
      for (int j = 0; j < 8; ++j) kv[j] = kp[j];
      float s0 = 0.f, s1 = 0.f, s2 = 0.f, s3 = 0.f;
#pragma unroll
      for (int j = 0; j < 8; ++j) {
        s0 = fmaf(q4[j].x, kv[j].x, s0);
        s1 = fmaf(q4[j].y, kv[j].y, s1);
        s2 = fmaf(q4[j].z, kv[j].z, s2);
        s3 = fmaf(q4[j].w, kv[j].w, s3);
      }
      float s = ((s0 + s1) + (s2 + s3)) * ATT_SCALE;
      float4 vv[8];
#pragma unroll
      for (int j = 0; j < 8; ++j) vv[j] = vp[j];
      if (s <= m) {                       // common path: no rescale
        float p = __expf(s - m);
        l += p;
#pragma unroll
        for (int j = 0; j < 8; ++j) {
          o4[j].x = fmaf(p, vv[j].x, o4[j].x);
          o4[j].y = fmaf(p, vv[j].y, o4[j].y);
          o4[j].z = fmaf(p, vv[j].z, o4[j].z);
          o4[j].w = fmaf(p, vv[j].w, o4[j].w);
        }
      } else {                            // new max: rescale, p == 1
        float corr = __expf(m - s);
        l = fmaf(l, corr, 1.0f);
#pragma unroll
        for (int j = 0; j < 8; ++j) {
          o4[j].x = fmaf(o4[j].x, corr, vv[j].x);
          o4[j].y = fmaf(o4[j].y, corr, vv[j].y);
          o4[j].z = fmaf(o4[j].z, corr, vv[j].z);
          o4[j].w = fmaf(o4[j].w, corr, vv[j].w);
        }
        m = s;
      }
    }
  }

  // publish per-wave partials
  if (act) {
    Pm[wave][lane] = m;
    Pl[wave][lane] = l;
#pragma unroll
    for (int j = 0; j < 8; ++j)
      *(float4*)&Po[wave][lane * 36 + 4 * j] = o4[j];
  }
  __syncthreads();

  // combine m,l across the 4 waves; fold 1/L into per-wave coefficients
  if (wave == 0 && act) {
    float m0 = Pm[0][lane], m1 = Pm[1][lane], m2 = Pm[2][lane], m3 = Pm[3][lane];
    float M = fmaxf(fmaxf(m0, m1), fmaxf(m2, m3));
    float e0 = __expf(m0 - M), e1 = __expf(m1 - M);
    float e2 = __expf(m2 - M), e3 = __expf(m3 - M);
    float L = Pl[0][lane] * e0 + Pl[1][lane] * e1 +
              Pl[2][lane] * e2 + Pl[3][lane] * e3;
    float inv = 1.0f / L;
    Pc[0][lane] = e0 * inv;
    Pc[1][lane] = e1 * inv;
    Pc[2][lane] = e2 * inv;
    Pc[3][lane] = e3 * inv;
  }
  __syncthreads();

  // weighted combine of the 4 partial O vectors; coalesced store
  for (int idx = tid; idx < 448; idx += 256) {   // 56 rows * 8 float4
    int row = idx >> 3, j = idx & 7;
    float4 acc = make_float4(0.f, 0.f, 0.f, 0.f);
#pragma unroll
    for (int w = 0; w < 4; ++w) {
      float c = Pc[w][row];
      float4 ov = *(const float4*)&Po[w][row * 36 + 4 * j];
      acc.x = fmaf(c, ov.x, acc.x);
      acc.y = fmaf(c, ov.y, acc.y);
      acc.z = fmaf(c, ov.z, acc.z);
      acc.w = fmaf(c, ov.w, acc.w);
    }
    *(float4*)&O[(size_t)(n * SS + qc * 56 + row) * DD + h * DKK + 4 * j] = acc;
  }
}

// ---------------- variable attention: N=672, L=8, one block per n ---------
__global__ __launch_bounds__(64) void k_attn_var(
    const float* __restrict__ Q, const float* __restrict__ K,
    const float* __restrict__ V, float* __restrict__ O) {
  int n = blockIdx.x;
  int tid = threadIdx.x;
  __shared__ float Ks[2080];
  __shared__ float Vs[2080];
  for (int f = tid; f < 512; f += 64) {   // 8 rows * 64 float4
    int l = f >> 6, c4 = f & 63, h = c4 >> 3, j = c4 & 7;
    float4 kv = ((const float4*)K)[(n * VV + l) * 64 + c4];
    *(float4*)&Ks[h * 260 + l * 32 + 4 * j] = kv;
    float4 vv = ((const float4*)V)[(n * VV + l) * 64 + c4];
    *(float4*)&Vs[h * 260 + l * 32 + 4 * j] = vv;
  }
  __syncthreads();
  int h = tid >> 3, qi = tid & 7;
  float4 q4[8];
  const float4* qp = (const float4*)&Q[(n * VV + qi) * DD + h * DKK];
#pragma unroll
  for (int j = 0; j < 8; ++j) q4[j] = qp[j];
  float sc[8];
#pragma unroll
  for (int k = 0; k < 8; ++k) {
    const float4* krow = (const float4*)&Ks[h * 260 + k * 32];
    float s0 = 0.f, s1 = 0.f, s2 = 0.f, s3 = 0.f;
#pragma unroll
    for (int j = 0; j < 8; ++j) {
      float4 kv = krow[j];
      s0 = fmaf(q4[j].x, kv.x, s0);
      s1 = fmaf(q4[j].y, kv.y, s1);
      s2 = fmaf(q4[j].z, kv.z, s2);
      s3 = fmaf(q4[j].w, kv.w, s3);
    }
    sc[k] = ((s0 + s1) + (s2 + s3)) * ATT_SCALE;
  }
  float mx = sc[0];
#pragma unroll
  for (int k = 1; k < 8; ++k) mx = fmaxf(mx, sc[k]);
  float psum = 0.f;
#pragma unroll
  for (int k = 0; k < 8; ++k) {
    sc[k] = __expf(sc[k] - mx);
    psum += sc[k];
  }
  float inv = 1.f / psum;
  float4* op = (float4*)&O[(n * VV + qi) * DD + h * DKK];
#pragma unroll
  for (int j = 0; j < 8; ++j) {
    float ax = 0.f, ay = 0.f, az = 0.f, aw = 0.f;
#pragma unroll
    for (int k = 0; k < 8; ++k) {
      float4 vv = *(const float4*)&Vs[h * 260 + k * 32 + 4 * j];
      ax = fmaf(sc[k], vv.x, ax);
      ay = fmaf(sc[k], vv.y, ay);
      az = fmaf(sc[k], vv.z, az);
      aw = fmaf(sc[k], vv.w, aw);
    }
    float4 o;
    o.x = ax * inv; o.y = ay * inv; o.z = az * inv; o.w = aw * inv;
    op[j] = o;
  }
}

// ---------------- LN helpers -----------------------------------------------
__global__ __launch_bounds__(256) void k_ln_double(
    const float* __restrict__ T, const float* __restrict__ g1,
    const float* __restrict__ c1, const float* __restrict__ g2,
    const float* __restrict__ c2, float* __restrict__ Ev) {
  int r = blockIdx.x * 4 + (threadIdx.x >> 6);
  int lane = threadIdx.x & 63;
  float4 xv = ((const float4*)T)[r * 64 + lane];
  float sum = xv.x + xv.y + xv.z + xv.w;
  float sq = fmaf(xv.x, xv.x, fmaf(xv.y, xv.y, fmaf(xv.z, xv.z, xv.w * xv.w)));
#pragma unroll
  for (int off = 32; off > 0; off >>= 1) {
    sum += __shfl_xor(sum, off);
    sq += __shfl_xor(sq, off);
  }
  float mean = sum * (1.0f / 256.0f);
  float var = sq * (1.0f / 256.0f) - mean * mean;
  float rstd = rsqrtf(var + LN_EPS);
  float4 gg = ((const float4*)g1)[lane];
  float4 bb = ((const float4*)c1)[lane];
  float4 z;
  z.x = fmaf((xv.x - mean) * rstd, gg.x, bb.x);
  z.y = fmaf((xv.y - mean) * rstd, gg.y, bb.y);
  z.z = fmaf((xv.z - mean) * rstd, gg.z, bb.z);
  z.w = fmaf((xv.w - mean) * rstd, gg.w, bb.w);
  float sum2 = z.x + z.y + z.z + z.w;
  float sq2 = fmaf(z.x, z.x, fmaf(z.y, z.y, fmaf(z.z, z.z, z.w * z.w)));
#pragma unroll
  for (int off = 32; off > 0; off >>= 1) {
    sum2 += __shfl_xor(sum2, off);
    sq2 += __shfl_xor(sq2, off);
  }
  float mean2 = sum2 * (1.0f / 256.0f);
  float var2 = sq2 * (1.0f / 256.0f) - mean2 * mean2;
  float rstd2 = rsqrtf(var2 + LN_EPS);
  float4 g2v = ((const float4*)g2)[lane];
  float4 b2v = ((const float4*)c2)[lane];
  float4 w;
  w.x = fmaf((z.x - mean2) * rstd2, g2v.x, b2v.x);
  w.y = fmaf((z.y - mean2) * rstd2, g2v.y, b2v.y);
  w.z = fmaf((z.z - mean2) * rstd2, g2v.z, b2v.z);
  w.w = fmaf((z.w - mean2) * rstd2, g2v.w, b2v.w);
  int n = r / SS;
  int sidx = r - n * SS;
  int b = n >> 3, v = n & 7;
  int r2 = (b * SS + sidx) * VV + v;
  ((float4*)Ev)[r2 * 64 + lane] = w;
}

__global__ __launch_bounds__(256) void k_ln_single(
    const float* __restrict__ T, const float* __restrict__ g1,
    const float* __restrict__ c1, float* __restrict__ Et) {
  int r = blockIdx.x * 4 + (threadIdx.x >> 6);
  int lane = threadIdx.x & 63;
  float4 xv = ((const float4*)T)[r * 64 + lane];
  float sum = xv.x + xv.y + xv.z + xv.w;
  float sq = fmaf(xv.x, xv.x, fmaf(xv.y, xv.y, fmaf(xv.z, xv.z, xv.w * xv.w)));
#pragma unroll
  for (int off = 32; off > 0; off >>= 1) {
    sum += __shfl_xor(sum, off);
    sq += __shfl_xor(sq, off);
  }
  float mean = sum * (1.0f / 256.0f);
  float var = sq * (1.0f / 256.0f) - mean * mean;
  float rstd = rsqrtf(var + LN_EPS);
  float4 gg = ((const float4*)g1)[lane];
  float4 bb = ((const float4*)c1)[lane];
  float4 w;
  w.x = fmaf((xv.x - mean) * rstd, gg.x, bb.x);
  w.y = fmaf((xv.y - mean) * rstd, gg.y, bb.y);
  w.z = fmaf((xv.z - mean) * rstd, gg.z, bb.z);
  w.w = fmaf((xv.w - mean) * rstd, gg.w, bb.w);
  int t = r >> 3;
  int v = r & 7;
  int b = t / SS;
  int sidx = t - b * SS;
  int r2 = (b * VV + v) * SS + sidx;
  ((float4*)Et)[r2 * 64 + lane] = w;
}

// ---------------- final projection -----------------------------------------
__global__ __launch_bounds__(384) void k_proj_partial(
    const float* __restrict__ E, const float* __restrict__ PW,
    float* __restrict__ Part) {
  int kc = blockIdx.x;            // 128 chunks of 672 k each
  int tid = threadIdx.x;
  int p = tid % 96, g = tid / 96; // 4 k-subgroups
  int kbase = kc * 672 + g * 168;
  float acc[16];
#pragma unroll
  for (int i = 0; i < 16; ++i) acc[i] = 0.f;
  for (int j = 0; j < 168; ++j) {
    int k = kbase + j;
    float w = PW[k * 96 + p];
#pragma unroll
    for (int i = 0; i < 16; ++i) acc[i] = fmaf(E[i * 86016 + k], w, acc[i]);
  }
  __shared__ float sm[16][384];
#pragma unroll
  for (int i = 0; i < 16; ++i) sm[i][tid] = acc[i];
  __syncthreads();
  if (tid < 96) {
#pragma unroll
    for (int i = 0; i < 16; ++i) {
      float ssum = sm[i][tid] + sm[i][96 + tid] + sm[i][192 + tid] + sm[i][288 + tid];
      int b = i >> 3, v = i & 7;
      Part[kc * 1536 + b * 768 + tid * 8 + v] = ssum;
    }
  }
}

__global__ __launch_bounds__(256) void k_proj_reduce(
    const float* __restrict__ Part, const float* __restrict__ PB,
    float* __restrict__ out) {
  int i = blockIdx.x * 256 + threadIdx.x;   // 1536 outputs [b][p][v]
  int p = (i % 768) >> 3;
  float ssum = PB[p];
  for (int c = 0; c < 128; ++c) ssum += Part[c * 1536 + i];
  out[i] = ssum;
}

// ---------------- launch ---------------------------------------------------
extern "C" void kernel_launch(void* const* d_in, const int* in_sizes, int n_in,
                              void* d_out, int out_size, void* d_ws,
                              size_t ws_size, hipStream_t stream) {
  const float* x     = (const float*)d_in[0];
  const float* emb_w = (const float*)d_in[1];
  const float* emb_b = (const float*)d_in[2];
  const float* Wq = (const float*)d_in[3];
  const float* bq = (const float*)d_in[4];
  const float* Wk = (const float*)d_in[5];
  const float* bk = (const float*)d_in[6];
  const float* Wv = (const float*)d_in[7];
  const float* bv = (const float*)d_in[8];
  const float* Wo = (const float*)d_in[9];
  const float* bo = (const float*)d_in[10];
  const float* g1 = (const float*)d_in[11];
  const float* b1 = (const float*)d_in[12];
  const float* gn = (const float*)d_in[13];
  const float* bn = (const float*)d_in[14];
  const float* PW = (const float*)d_in[15];
  const float* PB = (const float*)d_in[16];
  float* out = (float*)d_out;

  float* ws = (float*)d_ws;
  float* Etime = ws;
  float* Evar  = ws + (size_t)NTD;
  float* Qb    = ws + 2 * (size_t)NTD;
  float* Kb    = ws + 3 * (size_t)NTD;
  float* Vb    = ws + 4 * (size_t)NTD;
  float* AO    = ws + 5 * (size_t)NTD;
  float* T1    = ws + 6 * (size_t)NTD;
  float* Part  = ws + 7 * (size_t)NTD;  // 128*1536 floats

  k_embed<<<NTOK, 256, 0, stream>>>(x, emb_w, emb_b, Etime);
  for (int it = 0; it < 10; ++it) {
    // ---- attention over time axis (N=16, L=336) ----
    k_gemm<<<dim3(84, 4, 3), 256, 0, stream>>>(Etime, Wq, Wk, Wv, bq, bk, bv,
                                               Qb, Kb, Vb, nullptr);
    k_attn_time<<<dim3(6, 8, 16), 256, 0, stream>>>(Qb, Kb, Vb, AO);
    k_gemm<<<dim3(84, 4, 1), 256, 0, stream>>>(AO, Wo, Wo, Wo, bo, bo, bo,
                                               T1, T1, T1, Etime);
    k_ln_double<<<NTOK / 4, 256, 0, stream>>>(T1, g1, b1, gn, bn, Evar);
    // ---- attention over variable axis (N=672, L=8) ----
    k_gemm<<<dim3(84, 4, 3), 256, 0, stream>>>(Evar, Wq, Wk, Wv, bq, bk, bv,
                                               Qb, Kb, Vb, nullptr);
    k_attn_var<<<672, 64, 0, stream>>>(Qb, Kb, Vb, AO);
    k_gemm<<<dim3(84, 4, 1), 256, 0, stream>>>(AO, Wo, Wo, Wo, bo, bo, bo,
                                               T1, T1, T1, Evar);
    k_ln_single<<<NTOK / 4, 256, 0, stream>>>(T1, g1, b1, Etime);
  }
  k_proj_partial<<<128, 384, 0, stream>>>(Etime, PW, Part);
  k_proj_reduce<<<6, 256, 0, stream>>>(Part, PB, out);
}

// Round 4
// 1704.837 us; speedup vs baseline: 1.3258x; 1.1989x over previous
//
#include <hip/hip_runtime.h>

#define SS 336
#define VV 8
#define DD 256
#define DKK 32
#define NTOK 5376            // B*V*S = B*S*V tokens
#define NTD (NTOK * DD)      // 1376256 floats per activation buffer
#define ATT_SCALE 0.17677669529663687f  // 1/sqrt(32)
#define LN_EPS 1e-5f

typedef _Float16 f16x8 __attribute__((ext_vector_type(8)));
typedef _Float16 f16x4 __attribute__((ext_vector_type(4)));
typedef __attribute__((ext_vector_type(4))) float f32x4;

__device__ inline _Float16 f2h(float f) { return (_Float16)f; }

// ---------------- weight prep: WT[z][n][k] = f16(W_z[k][n]) ----------------
__global__ __launch_bounds__(256) void k_prep_w(
    const float* __restrict__ Wq, const float* __restrict__ Wk,
    const float* __restrict__ Wv, const float* __restrict__ Wo,
    _Float16* __restrict__ WT) {
  int z = blockIdx.y;
  const float* W = (z == 0) ? Wq : (z == 1) ? Wk : (z == 2) ? Wv : Wo;
  int o = blockIdx.x * 256 + threadIdx.x;   // 65536 per matrix
  int n = o >> 8, k = o & 255;
  WT[z * 65536 + n * 256 + k] = f2h(W[k * 256 + n]);
}

// ---------------- embed ----------------------------------------------------
__global__ __launch_bounds__(256) void k_embed(
    const float* __restrict__ x, const float* __restrict__ ew,
    const float* __restrict__ eb, float* __restrict__ E,
    _Float16* __restrict__ E16) {
  int token = blockIdx.x;            // (b*V+v)*S + s
  int n = token / SS, s = token - n * SS;
  int b = n >> 3, v = n & 7;
  float xv = x[(b * SS + s) * VV + v];
  int d = threadIdx.x;
  float val = fmaf(xv, ew[d], eb[d]);
  E[token * DD + d] = val;
  E16[token * DD + d] = f2h(val);
}

// ---------------- fp16 MFMA GEMM: Y = A[5376,256] @ W[256,256] + bias ------
// grid (42, 2, z); block 256 = 4 waves; 128x128 tile; K=256, BK=32.
// A16: f16 row-major [m][k]. wt*: f16 pre-transposed [n][k].
__global__ __launch_bounds__(256) void k_gemm_f16(
    const _Float16* __restrict__ A16,
    const _Float16* __restrict__ wt0,
    const _Float16* __restrict__ wt1,
    const _Float16* __restrict__ wt2,
    const float* __restrict__ c0, const float* __restrict__ c1,
    const float* __restrict__ c2,
    float* __restrict__ Y0, float* __restrict__ Y1, float* __restrict__ Y2,
    const float* __restrict__ Res) {
  int z = blockIdx.z;
  const _Float16* WT = (z == 0) ? wt0 : (z == 1) ? wt1 : wt2;
  const float* bias  = (z == 0) ? c0 : (z == 1) ? c1 : c2;
  float* Y           = (z == 0) ? Y0 : (z == 1) ? Y1 : Y2;
  int m0 = blockIdx.x * 128, n0 = blockIdx.y * 128;
  int tid = threadIdx.x;
  int wave = tid >> 6, lane = tid & 63;
  int wm = wave >> 1, wn = wave & 1;
  int lrow = lane & 15, kq = lane >> 4;

  // LDS layout: [kseg 0..3][row 0..127][8 f16] — 16B units
  __shared__ _Float16 As[4 * 128 * 8];
  __shared__ _Float16 Bs[4 * 128 * 8];

  f32x4 acc[4][4] = {};

  for (int k0 = 0; k0 < 256; k0 += 32) {
    __syncthreads();
#pragma unroll
    for (int p = 0; p < 2; ++p) {
      int row = p * 64 + lane;
      *(f16x8*)&As[(wave * 128 + row) * 8] =
          *(const f16x8*)&A16[(size_t)(m0 + row) * 256 + k0 + wave * 8];
      *(f16x8*)&Bs[(wave * 128 + row) * 8] =
          *(const f16x8*)&WT[(size_t)(n0 + row) * 256 + k0 + wave * 8];
    }
    __syncthreads();
    f16x8 af[4], bfr[4];
#pragma unroll
    for (int mt = 0; mt < 4; ++mt)
      af[mt] = *(const f16x8*)&As[(kq * 128 + wm * 64 + mt * 16 + lrow) * 8];
#pragma unroll
    for (int nt = 0; nt < 4; ++nt)
      bfr[nt] = *(const f16x8*)&Bs[(kq * 128 + wn * 64 + nt * 16 + lrow) * 8];
#pragma unroll
    for (int mt = 0; mt < 4; ++mt)
#pragma unroll
      for (int nt = 0; nt < 4; ++nt)
        acc[mt][nt] = __builtin_amdgcn_mfma_f32_16x16x32_f16(
            af[mt], bfr[nt], acc[mt][nt], 0, 0, 0);
  }

  // epilogue: C[row][col], col=lane&15, row=(lane>>4)*4+i
  int cb = n0 + wn * 64 + lrow;
  int rb = m0 + wm * 64 + kq * 4;
  float bsv[4];
#pragma unroll
  for (int nt = 0; nt < 4; ++nt) bsv[nt] = bias[cb + nt * 16];
#pragma unroll
  for (int mt = 0; mt < 4; ++mt) {
#pragma unroll
    for (int i = 0; i < 4; ++i) {
      int r = rb + mt * 16 + i;
#pragma unroll
      for (int nt = 0; nt < 4; ++nt) {
        int c = cb + nt * 16;
        float val = acc[mt][nt][i] + bsv[nt];
        if (Res) val += Res[(size_t)r * 256 + c];
        Y[(size_t)r * 256 + c] = val;
      }
    }
  }
}

// ---------------- time attention -------------------------------------------
// grid (6 qc, 8 h, 16 n), block 256 = 4 waves; output f16.
__global__ __launch_bounds__(256) void k_attn_time(
    const float* __restrict__ Q, const float* __restrict__ K,
    const float* __restrict__ V, _Float16* __restrict__ O16) {
  int qc = blockIdx.x, h = blockIdx.y, n = blockIdx.z;
  int tid = threadIdx.x;
  int wave = tid >> 6, lane = tid & 63;
  int wv = __builtin_amdgcn_readfirstlane(wave);
  bool act = (lane < 56);
  int qr = qc * 56 + lane;

  __shared__ float Pm[4][56];
  __shared__ float Pl[4][56];
  __shared__ float Pc[4][56];
  __shared__ float Po[4][56 * 36];

  float4 q4[8];
  float4 o4[8];
  float m = -1e30f, l = 0.f;
#pragma unroll
  for (int j = 0; j < 8; ++j) o4[j] = make_float4(0.f, 0.f, 0.f, 0.f);

  if (act) {
    const float4* qp = (const float4*)&Q[(size_t)(n * SS + qr) * DD + h * DKK];
#pragma unroll
    for (int j = 0; j < 8; ++j) q4[j] = qp[j];
    const float* Kb_ = K + (size_t)(n * SS + wv * 84) * DD + h * DKK;
    const float* Vb_ = V + (size_t)(n * SS + wv * 84) * DD + h * DKK;
    for (int kk = 0; kk < 84; ++kk) {
      const float4* kp = (const float4*)(Kb_ + (size_t)kk * DD);
      const float4* vp = (const float4*)(Vb_ + (size_t)kk * DD);
      float4 kv[8];
#pragma unroll
      for (int j = 0; j < 8; ++j) kv[j] = kp[j];
      float s0 = 0.f, s1 = 0.f, s2 = 0.f, s3 = 0.f;
#pragma unroll
      for (int j = 0; j < 8; ++j) {
        s0 = fmaf(q4[j].x, kv[j].x, s0);
        s1 = fmaf(q4[j].y, kv[j].y, s1);
        s2 = fmaf(q4[j].z, kv[j].z, s2);
        s3 = fmaf(q4[j].w, kv[j].w, s3);
      }
      float s = ((s0 + s1) + (s2 + s3)) * ATT_SCALE;
      float4 vv[8];
#pragma unroll
      for (int j = 0; j < 8; ++j) vv[j] = vp[j];
      if (s <= m) {
        float p = __expf(s - m);
        l += p;
#pragma unroll
        for (int j = 0; j < 8; ++j) {
          o4[j].x = fmaf(p, vv[j].x, o4[j].x);
          o4[j].y = fmaf(p, vv[j].y, o4[j].y);
          o4[j].z = fmaf(p, vv[j].z, o4[j].z);
          o4[j].w = fmaf(p, vv[j].w, o4[j].w);
        }
      } else {
        float corr = __expf(m - s);
        l = fmaf(l, corr, 1.0f);
#pragma unroll
        for (int j = 0; j < 8; ++j) {
          o4[j].x = fmaf(o4[j].x, corr, vv[j].x);
          o4[j].y = fmaf(o4[j].y, corr, vv[j].y);
          o4[j].z = fmaf(o4[j].z, corr, vv[j].z);
          o4[j].w = fmaf(o4[j].w, corr, vv[j].w);
        }
        m = s;
      }
    }
  }

  if (act) {
    Pm[wave][lane] = m;
    Pl[wave][lane] = l;
#pragma unroll
    for (int j = 0; j < 8; ++j)
      *(float4*)&Po[wave][lane * 36 + 4 * j] = o4[j];
  }
  __syncthreads();

  if (wave == 0 && act) {
    float m0 = Pm[0][lane], m1 = Pm[1][lane], m2 = Pm[2][lane], m3 = Pm[3][lane];
    float M = fmaxf(fmaxf(m0, m1), fmaxf(m2, m3));
    float e0 = __expf(m0 - M), e1 = __expf(m1 - M);
    float e2 = __expf(m2 - M), e3 = __expf(m3 - M);
    float L = Pl[0][lane] * e0 + Pl[1][lane] * e1 +
              Pl[2][lane] * e2 + Pl[3][lane] * e3;
    float inv = 1.0f / L;
    Pc[0][lane] = e0 * inv;
    Pc[1][lane] = e1 * inv;
    Pc[2][lane] = e2 * inv;
    Pc[3][lane] = e3 * inv;
  }
  __syncthreads();

  for (int idx = tid; idx < 448; idx += 256) {   // 56 rows * 8 float4
    int row = idx >> 3, j = idx & 7;
    float4 acc = make_float4(0.f, 0.f, 0.f, 0.f);
#pragma unroll
    for (int w = 0; w < 4; ++w) {
      float c = Pc[w][row];
      float4 ov = *(const float4*)&Po[w][row * 36 + 4 * j];
      acc.x = fmaf(c, ov.x, acc.x);
      acc.y = fmaf(c, ov.y, acc.y);
      acc.z = fmaf(c, ov.z, acc.z);
      acc.w = fmaf(c, ov.w, acc.w);
    }
    f16x4 o16 = { f2h(acc.x), f2h(acc.y), f2h(acc.z), f2h(acc.w) };
    *(f16x4*)&O16[(size_t)(n * SS + qc * 56 + row) * DD + h * DKK + 4 * j] = o16;
  }
}

// ---------------- variable attention: N=672, L=8 ---------------------------
__global__ __launch_bounds__(64) void k_attn_var(
    const float* __restrict__ Q, const float* __restrict__ K,
    const float* __restrict__ V, _Float16* __restrict__ O16) {
  int n = blockIdx.x;
  int tid = threadIdx.x;
  __shared__ float Ks[2080];
  __shared__ float Vs[2080];
  for (int f = tid; f < 512; f += 64) {   // 8 rows * 64 float4
    int l = f >> 6, c4 = f & 63, h = c4 >> 3, j = c4 & 7;
    float4 kv = ((const float4*)K)[(n * VV + l) * 64 + c4];
    *(float4*)&Ks[h * 260 + l * 32 + 4 * j] = kv;
    float4 vvv = ((const float4*)V)[(n * VV + l) * 64 + c4];
    *(float4*)&Vs[h * 260 + l * 32 + 4 * j] = vvv;
  }
  __syncthreads();
  int h = tid >> 3, qi = tid & 7;
  float4 q4[8];
  const float4* qp = (const float4*)&Q[(n * VV + qi) * DD + h * DKK];
#pragma unroll
  for (int j = 0; j < 8; ++j) q4[j] = qp[j];
  float sc[8];
#pragma unroll
  for (int k = 0; k < 8; ++k) {
    const float4* krow = (const float4*)&Ks[h * 260 + k * 32];
    float s0 = 0.f, s1 = 0.f, s2 = 0.f, s3 = 0.f;
#pragma unroll
    for (int j = 0; j < 8; ++j) {
      float4 kv = krow[j];
      s0 = fmaf(q4[j].x, kv.x, s0);
      s1 = fmaf(q4[j].y, kv.y, s1);
      s2 = fmaf(q4[j].z, kv.z, s2);
      s3 = fmaf(q4[j].w, kv.w, s3);
    }
    sc[k] = ((s0 + s1) + (s2 + s3)) * ATT_SCALE;
  }
  float mx = sc[0];
#pragma unroll
  for (int k = 1; k < 8; ++k) mx = fmaxf(mx, sc[k]);
  float psum = 0.f;
#pragma unroll
  for (int k = 0; k < 8; ++k) {
    sc[k] = __expf(sc[k] - mx);
    psum += sc[k];
  }
  float inv = 1.f / psum;
#pragma unroll
  for (int j = 0; j < 8; ++j) {
    float ax = 0.f, ay = 0.f, az = 0.f, aw = 0.f;
#pragma unroll
    for (int k = 0; k < 8; ++k) {
      float4 vv = *(const float4*)&Vs[h * 260 + k * 32 + 4 * j];
      ax = fmaf(sc[k], vv.x, ax);
      ay = fmaf(sc[k], vv.y, ay);
      az = fmaf(sc[k], vv.z, az);
      aw = fmaf(sc[k], vv.w, aw);
    }
    f16x4 o16 = { f2h(ax * inv), f2h(ay * inv), f2h(az * inv), f2h(aw * inv) };
    *(f16x4*)&O16[(size_t)(n * VV + qi) * DD + h * DKK + 4 * j] = o16;
  }
}

// ---------------- LN helpers -----------------------------------------------
__global__ __launch_bounds__(256) void k_ln_double(
    const float* __restrict__ T, const float* __restrict__ g1,
    const float* __restrict__ c1, const float* __restrict__ g2,
    const float* __restrict__ c2, float* __restrict__ Ev,
    _Float16* __restrict__ Ev16) {
  int r = blockIdx.x * 4 + (threadIdx.x >> 6);
  int lane = threadIdx.x & 63;
  float4 xv = ((const float4*)T)[r * 64 + lane];
  float sum = xv.x + xv.y + xv.z + xv.w;
  float sq = fmaf(xv.x, xv.x, fmaf(xv.y, xv.y, fmaf(xv.z, xv.z, xv.w * xv.w)));
#pragma unroll
  for (int off = 32; off > 0; off >>= 1) {
    sum += __shfl_xor(sum, off);
    sq += __shfl_xor(sq, off);
  }
  float mean = sum * (1.0f / 256.0f);
  float var = sq * (1.0f / 256.0f) - mean * mean;
  float rstd = rsqrtf(var + LN_EPS);
  float4 gg = ((const float4*)g1)[lane];
  float4 bb = ((const float4*)c1)[lane];
  float4 z;
  z.x = fmaf((xv.x - mean) * rstd, gg.x, bb.x);
  z.y = fmaf((xv.y - mean) * rstd, gg.y, bb.y);
  z.z = fmaf((xv.z - mean) * rstd, gg.z, bb.z);
  z.w = fmaf((xv.w - mean) * rstd, gg.w, bb.w);
  float sum2 = z.x + z.y + z.z + z.w;
  float sq2 = fmaf(z.x, z.x, fmaf(z.y, z.y, fmaf(z.z, z.z, z.w * z.w)));
#pragma unroll
  for (int off = 32; off > 0; off >>= 1) {
    sum2 += __shfl_xor(sum2, off);
    sq2 += __shfl_xor(sq2, off);
  }
  float mean2 = sum2 * (1.0f / 256.0f);
  float var2 = sq2 * (1.0f / 256.0f) - mean2 * mean2;
  float rstd2 = rsqrtf(var2 + LN_EPS);
  float4 g2v = ((const float4*)g2)[lane];
  float4 b2v = ((const float4*)c2)[lane];
  float4 w;
  w.x = fmaf((z.x - mean2) * rstd2, g2v.x, b2v.x);
  w.y = fmaf((z.y - mean2) * rstd2, g2v.y, b2v.y);
  w.z = fmaf((z.z - mean2) * rstd2, g2v.z, b2v.z);
  w.w = fmaf((z.w - mean2) * rstd2, g2v.w, b2v.w);
  int n = r / SS;
  int sidx = r - n * SS;
  int b = n >> 3, v = n & 7;
  int r2 = (b * SS + sidx) * VV + v;
  ((float4*)Ev)[r2 * 64 + lane] = w;
  f16x4 h16 = { f2h(w.x), f2h(w.y), f2h(w.z), f2h(w.w) };
  *(f16x4*)&Ev16[(size_t)r2 * 256 + lane * 4] = h16;
}

__global__ __launch_bounds__(256) void k_ln_single(
    const float* __restrict__ T, const float* __restrict__ g1,
    const float* __restrict__ c1, float* __restrict__ Et,
    _Float16* __restrict__ Et16) {
  int r = blockIdx.x * 4 + (threadIdx.x >> 6);
  int lane = threadIdx.x & 63;
  float4 xv = ((const float4*)T)[r * 64 + lane];
  float sum = xv.x + xv.y + xv.z + xv.w;
  float sq = fmaf(xv.x, xv.x, fmaf(xv.y, xv.y, fmaf(xv.z, xv.z, xv.w * xv.w)));
#pragma unroll
  for (int off = 32; off > 0; off >>= 1) {
    sum += __shfl_xor(sum, off);
    sq += __shfl_xor(sq, off);
  }
  float mean = sum * (1.0f / 256.0f);
  float var = sq * (1.0f / 256.0f) - mean * mean;
  float rstd = rsqrtf(var + LN_EPS);
  float4 gg = ((const float4*)g1)[lane];
  float4 bb = ((const float4*)c1)[lane];
  float4 w;
  w.x = fmaf((xv.x - mean) * rstd, gg.x, bb.x);
  w.y = fmaf((xv.y - mean) * rstd, gg.y, bb.y);
  w.z = fmaf((xv.z - mean) * rstd, gg.z, bb.z);
  w.w = fmaf((xv.w - mean) * rstd, gg.w, bb.w);
  int t = r >> 3;
  int v = r & 7;
  int b = t / SS;
  int sidx = t - b * SS;
  int r2 = (b * VV + v) * SS + sidx;
  ((float4*)Et)[r2 * 64 + lane] = w;
  f16x4 h16 = { f2h(w.x), f2h(w.y), f2h(w.z), f2h(w.w) };
  *(f16x4*)&Et16[(size_t)r2 * 256 + lane * 4] = h16;
}

// ---------------- final projection -----------------------------------------
// grid 672 (k-chunks of 128), block 192 = 24 p4-groups x 8 k-subgroups
__global__ __launch_bounds__(192) void k_proj_partial(
    const float* __restrict__ E, const float* __restrict__ PW,
    float* __restrict__ Part) {
  int kc = blockIdx.x;
  int tid = threadIdx.x;
  int p4 = tid % 24, g = tid / 24;
  __shared__ float Es[16][128];
  __shared__ float sm[8][1536];
  for (int idx = tid; idx < 512; idx += 192) {   // 16 rows * 32 float4
    int row = idx >> 5, kk4 = idx & 31;
    *(float4*)&Es[row][kk4 * 4] =
        *(const float4*)&E[(size_t)row * 86016 + kc * 128 + kk4 * 4];
  }
  __syncthreads();
  float4 acc[16];
#pragma unroll
  for (int i = 0; i < 16; ++i) acc[i] = make_float4(0.f, 0.f, 0.f, 0.f);
  for (int j = 0; j < 16; ++j) {
    int k = g * 16 + j;
    float4 w = *(const float4*)&PW[(size_t)(kc * 128 + k) * 96 + p4 * 4];
#pragma unroll
    for (int row = 0; row < 16; ++row) {
      float e = Es[row][k];
      acc[row].x = fmaf(e, w.x, acc[row].x);
      acc[row].y = fmaf(e, w.y, acc[row].y);
      acc[row].z = fmaf(e, w.z, acc[row].z);
      acc[row].w = fmaf(e, w.w, acc[row].w);
    }
  }
#pragma unroll
  for (int row = 0; row < 16; ++row)
    *(float4*)&sm[g][row * 96 + p4 * 4] = acc[row];
  __syncthreads();
  for (int o = tid; o < 1536; o += 192) {   // o = row*96 + p
    float s = 0.f;
#pragma unroll
    for (int g2 = 0; g2 < 8; ++g2) s += sm[g2][o];
    Part[(size_t)kc * 1536 + o] = s;
  }
}

__global__ __launch_bounds__(256) void k_proj_reduce1(
    const float* __restrict__ Part, float* __restrict__ out2) {
  int blk = blockIdx.x;               // 48 = 8 cb * 6 ib
  int cb = blk / 6, ib = blk % 6;
  int i = ib * 256 + threadIdx.x;     // i = row*96 + p
  float s = 0.f;
  for (int c = cb * 84; c < cb * 84 + 84; ++c) s += Part[(size_t)c * 1536 + i];
  out2[cb * 1536 + i] = s;
}

__global__ __launch_bounds__(256) void k_proj_reduce2(
    const float* __restrict__ out2, const float* __restrict__ PB,
    float* __restrict__ out) {
  int j = blockIdx.x * 256 + threadIdx.x;   // j = row*96 + p
  int row = j / 96, p = j - row * 96;
  float s = PB[p];
#pragma unroll
  for (int cb = 0; cb < 8; ++cb) s += out2[cb * 1536 + j];
  int b = row >> 3, v = row & 7;
  out[b * 768 + p * 8 + v] = s;
}

// ---------------- launch ---------------------------------------------------
extern "C" void kernel_launch(void* const* d_in, const int* in_sizes, int n_in,
                              void* d_out, int out_size, void* d_ws,
                              size_t ws_size, hipStream_t stream) {
  const float* x     = (const float*)d_in[0];
  const float* emb_w = (const float*)d_in[1];
  const float* emb_b = (const float*)d_in[2];
  const float* Wq = (const float*)d_in[3];
  const float* bq = (const float*)d_in[4];
  const float* Wk = (const float*)d_in[5];
  const float* bk = (const float*)d_in[6];
  const float* Wv = (const float*)d_in[7];
  const float* bv = (const float*)d_in[8];
  const float* Wo = (const float*)d_in[9];
  const float* bo = (const float*)d_in[10];
  const float* g1 = (const float*)d_in[11];
  const float* b1 = (const float*)d_in[12];
  const float* gn = (const float*)d_in[13];
  const float* bn = (const float*)d_in[14];
  const float* PW = (const float*)d_in[15];
  const float* PB = (const float*)d_in[16];
  float* out = (float*)d_out;

  float* ws = (float*)d_ws;
  float* Etime = ws;                       // NTD fp32
  float* Evar  = ws + (size_t)NTD;         // NTD fp32
  float* Qb    = ws + 2 * (size_t)NTD;     // NTD fp32 (reused: Part)
  float* Kb    = ws + 3 * (size_t)NTD;     // NTD fp32 (reused: out2)
  float* Vb    = ws + 4 * (size_t)NTD;     // NTD fp32
  float* T1    = ws + 5 * (size_t)NTD;     // NTD fp32
  _Float16* AO16 = (_Float16*)(ws + 6 * (size_t)NTD);
  _Float16* Et16 = (_Float16*)(ws + 6 * (size_t)NTD + NTD / 2);
  _Float16* Ev16 = (_Float16*)(ws + 7 * (size_t)NTD);
  _Float16* WT   = (_Float16*)(ws + 7 * (size_t)NTD + NTD / 2);
  float* Part = Qb;
  float* out2 = Kb;

  k_prep_w<<<dim3(256, 4), 256, 0, stream>>>(Wq, Wk, Wv, Wo, WT);
  k_embed<<<NTOK, 256, 0, stream>>>(x, emb_w, emb_b, Etime, Et16);
  for (int it = 0; it < 10; ++it) {
    // ---- attention over time axis (N=16, L=336) ----
    k_gemm_f16<<<dim3(42, 2, 3), 256, 0, stream>>>(
        Et16, WT, WT + 65536, WT + 2 * 65536, bq, bk, bv, Qb, Kb, Vb, nullptr);
    k_attn_time<<<dim3(6, 8, 16), 256, 0, stream>>>(Qb, Kb, Vb, AO16);
    k_gemm_f16<<<dim3(42, 2, 1), 256, 0, stream>>>(
        AO16, WT + 3 * 65536, WT + 3 * 65536, WT + 3 * 65536, bo, bo, bo,
        T1, T1, T1, Etime);
    k_ln_double<<<NTOK / 4, 256, 0, stream>>>(T1, g1, b1, gn, bn, Evar, Ev16);
    // ---- attention over variable axis (N=672, L=8) ----
    k_gemm_f16<<<dim3(42, 2, 3), 256, 0, stream>>>(
        Ev16, WT, WT + 65536, WT + 2 * 65536, bq, bk, bv, Qb, Kb, Vb, nullptr);
    k_attn_var<<<672, 64, 0, stream>>>(Qb, Kb, Vb, AO16);
    k_gemm_f16<<<dim3(42, 2, 1), 256, 0, stream>>>(
        AO16, WT + 3 * 65536, WT + 3 * 65536, WT + 3 * 65536, bo, bo, bo,
        T1, T1, T1, Evar);
    k_ln_single<<<NTOK / 4, 256, 0, stream>>>(T1, g1, b1, Etime, Et16);
  }
  k_proj_partial<<<672, 192, 0, stream>>>(Etime, PW, Part);
  k_proj_reduce1<<<48, 256, 0, stream>>>(Part, out2);
  k_proj_reduce2<<<6, 256, 0, stream>>>(out2, PB, out);
}

// Round 5
// 1214.694 us; speedup vs baseline: 1.8607x; 1.4035x over previous
//
#include <hip/hip_runtime.h>

#define SS 336
#define VV 8
#define DD 256
#define DKK 32
#define NTOK 5376            // B*V*S = B*S*V tokens
#define NTD (NTOK * DD)      // 1376256 elements per activation buffer
#define ATT_SCALE 0.17677669529663687f  // 1/sqrt(32)
#define LN_EPS 1e-5f

typedef _Float16 f16x8 __attribute__((ext_vector_type(8)));
typedef _Float16 f16x4v __attribute__((ext_vector_type(4)));
typedef __attribute__((ext_vector_type(4))) float f32x4;

__device__ inline _Float16 f2h(float f) { return (_Float16)f; }

// ---------------- weight prep: WT[z][n][k] = f16(W_z[k][n]) ----------------
__global__ __launch_bounds__(256) void k_prep_w(
    const float* __restrict__ Wq, const float* __restrict__ Wk,
    const float* __restrict__ Wv, const float* __restrict__ Wo,
    _Float16* __restrict__ WT) {
  int z = blockIdx.y;
  const float* W = (z == 0) ? Wq : (z == 1) ? Wk : (z == 2) ? Wv : Wo;
  int o = blockIdx.x * 256 + threadIdx.x;   // 65536 per matrix
  int n = o >> 8, k = o & 255;
  WT[z * 65536 + n * 256 + k] = f2h(W[k * 256 + n]);
}

// ---------------- embed ----------------------------------------------------
__global__ __launch_bounds__(256) void k_embed(
    const float* __restrict__ x, const float* __restrict__ ew,
    const float* __restrict__ eb, float* __restrict__ E,
    _Float16* __restrict__ E16) {
  int token = blockIdx.x;            // (b*V+v)*S + s
  int n = token / SS, s = token - n * SS;
  int b = n >> 3, v = n & 7;
  float xv = x[(b * SS + s) * VV + v];
  int d = threadIdx.x;
  float val = fmaf(xv, ew[d], eb[d]);
  E[token * DD + d] = val;
  E16[token * DD + d] = f2h(val);
}

// ---------------- fp16 MFMA GEMM: Y = A[5376,256] @ W[256,256] + bias ------
// grid (42, 2, z); block 256 = 4 waves; 128x128 tile; K=256, BK=32.
// f16 outputs (H*) for QKV, or f32 (Yf) + residual for O-proj.
__global__ __launch_bounds__(256) void k_gemm_f16(
    const _Float16* __restrict__ A16,
    const _Float16* __restrict__ wt0,
    const _Float16* __restrict__ wt1,
    const _Float16* __restrict__ wt2,
    const float* __restrict__ c0, const float* __restrict__ c1,
    const float* __restrict__ c2,
    _Float16* __restrict__ H0, _Float16* __restrict__ H1,
    _Float16* __restrict__ H2,
    float* __restrict__ Yf, const float* __restrict__ Res) {
  int z = blockIdx.z;
  const _Float16* WT = (z == 0) ? wt0 : (z == 1) ? wt1 : wt2;
  const float* bias  = (z == 0) ? c0 : (z == 1) ? c1 : c2;
  _Float16* H        = (z == 0) ? H0 : (z == 1) ? H1 : H2;
  int m0 = blockIdx.x * 128, n0 = blockIdx.y * 128;
  int tid = threadIdx.x;
  int wave = tid >> 6, lane = tid & 63;
  int wm = wave >> 1, wn = wave & 1;
  int lrow = lane & 15, kq = lane >> 4;

  __shared__ _Float16 As[4 * 128 * 8];
  __shared__ _Float16 Bs[4 * 128 * 8];

  f32x4 acc[4][4] = {};

  for (int k0 = 0; k0 < 256; k0 += 32) {
    __syncthreads();
#pragma unroll
    for (int p = 0; p < 2; ++p) {
      int row = p * 64 + lane;
      *(f16x8*)&As[(wave * 128 + row) * 8] =
          *(const f16x8*)&A16[(size_t)(m0 + row) * 256 + k0 + wave * 8];
      *(f16x8*)&Bs[(wave * 128 + row) * 8] =
          *(const f16x8*)&WT[(size_t)(n0 + row) * 256 + k0 + wave * 8];
    }
    __syncthreads();
    f16x8 af[4], bfr[4];
#pragma unroll
    for (int mt = 0; mt < 4; ++mt)
      af[mt] = *(const f16x8*)&As[(kq * 128 + wm * 64 + mt * 16 + lrow) * 8];
#pragma unroll
    for (int nt = 0; nt < 4; ++nt)
      bfr[nt] = *(const f16x8*)&Bs[(kq * 128 + wn * 64 + nt * 16 + lrow) * 8];
#pragma unroll
    for (int mt = 0; mt < 4; ++mt)
#pragma unroll
      for (int nt = 0; nt < 4; ++nt)
        acc[mt][nt] = __builtin_amdgcn_mfma_f32_16x16x32_f16(
            af[mt], bfr[nt], acc[mt][nt], 0, 0, 0);
  }

  // epilogue: C[row][col], col=lane&15, row=(lane>>4)*4+i
  int cb = n0 + wn * 64 + lrow;
  int rb = m0 + wm * 64 + kq * 4;
  float bsv[4];
#pragma unroll
  for (int nt = 0; nt < 4; ++nt) bsv[nt] = bias[cb + nt * 16];
#pragma unroll
  for (int mt = 0; mt < 4; ++mt) {
#pragma unroll
    for (int i = 0; i < 4; ++i) {
      int r = rb + mt * 16 + i;
#pragma unroll
      for (int nt = 0; nt < 4; ++nt) {
        int c = cb + nt * 16;
        float val = acc[mt][nt][i] + bsv[nt];
        if (H) {
          H[(size_t)r * 256 + c] = f2h(val);
        } else {
          if (Res) val += Res[(size_t)r * 256 + c];
          Yf[(size_t)r * 256 + c] = val;
        }
      }
    }
  }
}

// ---------------- time attention: MFMA flash, f16 in/out -------------------
// grid (6 qg, 8 h, 16 n), block 256 = 4 waves; wave w handles q-tile qg*4+w
// (16 q rows). K staged [336][36] f16; V staged transposed Vt[32][344] f16.
#define KSTR 36
#define VTSTR 344
__global__ __launch_bounds__(256) void k_attn_time(
    const _Float16* __restrict__ Q, const _Float16* __restrict__ K,
    const _Float16* __restrict__ V, _Float16* __restrict__ O16) {
  int qg = blockIdx.x, h = blockIdx.y, n = blockIdx.z;
  int tid = threadIdx.x;
  int wave = tid >> 6, lane = tid & 63;
  int quad = lane >> 4, lcol = lane & 15;

  __shared__ _Float16 Ks[336 * KSTR];          // 24192 B
  __shared__ _Float16 Vt[32 * VTSTR + 16];     // 22048 B
  __shared__ _Float16 Ps[4][16 * 40];          // 5120 B

  const size_t base = (size_t)(n * SS) * DD + h * DKK;

  // stage K rows and transposed V
  for (int c = tid; c < 1344; c += 256) {      // 336 rows * 4 chunks(8 f16)
    int row = c >> 2, part = c & 3;
    f16x8 kv = *(const f16x8*)&K[base + (size_t)row * DD + part * 8];
    f16x4v klo = __builtin_shufflevector(kv, kv, 0, 1, 2, 3);
    f16x4v khi = __builtin_shufflevector(kv, kv, 4, 5, 6, 7);
    *(f16x4v*)&Ks[row * KSTR + part * 8] = klo;
    *(f16x4v*)&Ks[row * KSTR + part * 8 + 4] = khi;
    f16x8 vv = *(const f16x8*)&V[base + (size_t)row * DD + part * 8];
#pragma unroll
    for (int j = 0; j < 8; ++j) Vt[(part * 8 + j) * VTSTR + row] = vv[j];
  }
  // zero Vt pad (cols 336..343 and tail guard)
  for (int c = tid; c < 272; c += 256) {
    if (c < 256) {
      int d = c >> 3, col = 336 + (c & 7);
      Vt[d * VTSTR + col] = (_Float16)0.f;
    } else {
      Vt[32 * VTSTR + (c - 256)] = (_Float16)0.f;
    }
  }
  __syncthreads();

  int qtile = qg * 4 + wave;
  if (qtile >= 21) return;
  int qb = qtile * 16;

  f16x8 qf = *(const f16x8*)&Q[base + (size_t)(qb + lcol) * DD + quad * 8];
  f32x4 accA = {0.f, 0.f, 0.f, 0.f};   // d = lcol
  f32x4 accB = {0.f, 0.f, 0.f, 0.f};   // d = 16+lcol
  f32x4 lacc = {0.f, 0.f, 0.f, 0.f};   // rowsum accumulator
  float m_[4] = {-1e30f, -1e30f, -1e30f, -1e30f};
  _Float16* P = Ps[wave];
  const f16x8 onesv = {(_Float16)1.f, (_Float16)1.f, (_Float16)1.f, (_Float16)1.f,
                       (_Float16)1.f, (_Float16)1.f, (_Float16)1.f, (_Float16)1.f};
  const f32x4 z4 = {0.f, 0.f, 0.f, 0.f};

  for (int t = 0; t < 11; ++t) {
    int k0 = t * 32;
    bool full = (t < 10);
    // K B-frags (2 x b64 each, stride 36 keeps banks spread)
    const _Float16* kp0 = &Ks[(k0 + lcol) * KSTR + quad * 8];
    f16x4v ka = *(const f16x4v*)kp0;
    f16x4v kb = *(const f16x4v*)(kp0 + 4);
    f16x8 kf0 = __builtin_shufflevector(ka, kb, 0, 1, 2, 3, 4, 5, 6, 7);
    f32x4 s0 = __builtin_amdgcn_mfma_f32_16x16x32_f16(qf, kf0, z4, 0, 0, 0);
    f32x4 s1 = z4;
    if (full) {
      const _Float16* kp1 = &Ks[(k0 + 16 + lcol) * KSTR + quad * 8];
      f16x4v ka1 = *(const f16x4v*)kp1;
      f16x4v kb1 = *(const f16x4v*)(kp1 + 4);
      f16x8 kf1 = __builtin_shufflevector(ka1, kb1, 0, 1, 2, 3, 4, 5, 6, 7);
      s1 = __builtin_amdgcn_mfma_f32_16x16x32_f16(qf, kf1, z4, 0, 0, 0);
    }
    float sc0[4], sc1[4], p0[4], p1[4], corr[4];
#pragma unroll
    for (int i = 0; i < 4; ++i) {
      sc0[i] = s0[i] * ATT_SCALE;
      sc1[i] = full ? s1[i] * ATT_SCALE : -1e30f;
    }
    // per-row max over 16 score columns (lanes lcol within the quad group)
#pragma unroll
    for (int i = 0; i < 4; ++i) {
      float t2 = fmaxf(sc0[i], sc1[i]);
      t2 = fmaxf(t2, __shfl_xor(t2, 1));
      t2 = fmaxf(t2, __shfl_xor(t2, 2));
      t2 = fmaxf(t2, __shfl_xor(t2, 4));
      t2 = fmaxf(t2, __shfl_xor(t2, 8));
      float nm = fmaxf(m_[i], t2);
      corr[i] = __expf(m_[i] - nm);
      m_[i] = nm;
      p0[i] = __expf(sc0[i] - nm);
      p1[i] = __expf(sc1[i] - nm);
      accA[i] *= corr[i];
      accB[i] *= corr[i];
      lacc[i] *= corr[i];
    }
    // P: C-layout -> A-layout via per-wave LDS tile (stride 40)
#pragma unroll
    for (int i = 0; i < 4; ++i) {
      P[(quad * 4 + i) * 40 + lcol] = f2h(p0[i]);
      P[(quad * 4 + i) * 40 + 16 + lcol] = f2h(p1[i]);
    }
    f16x8 pf = *(const f16x8*)&P[lcol * 40 + quad * 8];
    // rowsum via ones-MFMA (replaces 16 shuffles)
    lacc = __builtin_amdgcn_mfma_f32_16x16x32_f16(pf, onesv, lacc, 0, 0, 0);
    // PV
    f16x8 vb0 = *(const f16x8*)&Vt[lcol * VTSTR + k0 + quad * 8];
    f16x8 vb1 = *(const f16x8*)&Vt[(16 + lcol) * VTSTR + k0 + quad * 8];
    accA = __builtin_amdgcn_mfma_f32_16x16x32_f16(pf, vb0, accA, 0, 0, 0);
    accB = __builtin_amdgcn_mfma_f32_16x16x32_f16(pf, vb1, accB, 0, 0, 0);
  }

  // normalize and store via LDS tile (coalesced f16x8 stores)
#pragma unroll
  for (int i = 0; i < 4; ++i) {
    float inv = 1.f / lacc[i];
    P[(quad * 4 + i) * 40 + lcol] = f2h(accA[i] * inv);
    P[(quad * 4 + i) * 40 + 16 + lcol] = f2h(accB[i] * inv);
  }
  int row = lane >> 2, seg = lane & 3;
  f16x8 ov = *(const f16x8*)&P[row * 40 + seg * 8];
  *(f16x8*)&O16[base + (size_t)(qb + row) * DD + seg * 8] = ov;
}

// ---------------- variable attention: N=672, L=8, f16 in/out ---------------
__global__ __launch_bounds__(64) void k_attn_var(
    const _Float16* __restrict__ Q, const _Float16* __restrict__ K,
    const _Float16* __restrict__ V, _Float16* __restrict__ O16) {
  int n = blockIdx.x;
  int tid = threadIdx.x;
  __shared__ float Ks[2080];
  __shared__ float Vs[2080];
  for (int f = tid; f < 256; f += 64) {   // 8 rows * 32 chunks(8 f16)
    int l = f >> 5, c8 = f & 31, hh = c8 >> 2, j8 = c8 & 3;
    f16x8 kv = *(const f16x8*)&K[(size_t)(n * VV + l) * DD + c8 * 8];
    f16x8 vv = *(const f16x8*)&V[(size_t)(n * VV + l) * DD + c8 * 8];
    float* kd = &Ks[hh * 260 + l * 32 + j8 * 8];
    float* vd = &Vs[hh * 260 + l * 32 + j8 * 8];
#pragma unroll
    for (int j = 0; j < 8; ++j) {
      kd[j] = (float)kv[j];
      vd[j] = (float)vv[j];
    }
  }
  __syncthreads();
  int h = tid >> 3, qi = tid & 7;
  float4 q4[8];
  const _Float16* qp = &Q[(size_t)(n * VV + qi) * DD + h * DKK];
#pragma unroll
  for (int j4 = 0; j4 < 4; ++j4) {
    f16x8 qv = *(const f16x8*)&qp[j4 * 8];
    q4[2 * j4] = make_float4((float)qv[0], (float)qv[1], (float)qv[2], (float)qv[3]);
    q4[2 * j4 + 1] = make_float4((float)qv[4], (float)qv[5], (float)qv[6], (float)qv[7]);
  }
  float sc[8];
#pragma unroll
  for (int k = 0; k < 8; ++k) {
    const float4* krow = (const float4*)&Ks[h * 260 + k * 32];
    float s0 = 0.f, s1 = 0.f, s2 = 0.f, s3 = 0.f;
#pragma unroll
    for (int j = 0; j < 8; ++j) {
      float4 kv = krow[j];
      s0 = fmaf(q4[j].x, kv.x, s0);
      s1 = fmaf(q4[j].y, kv.y, s1);
      s2 = fmaf(q4[j].z, kv.z, s2);
      s3 = fmaf(q4[j].w, kv.w, s3);
    }
    sc[k] = ((s0 + s1) + (s2 + s3)) * ATT_SCALE;
  }
  float mx = sc[0];
#pragma unroll
  for (int k = 1; k < 8; ++k) mx = fmaxf(mx, sc[k]);
  float psum = 0.f;
#pragma unroll
  for (int k = 0; k < 8; ++k) {
    sc[k] = __expf(sc[k] - mx);
    psum += sc[k];
  }
  float inv = 1.f / psum;
#pragma unroll
  for (int j = 0; j < 8; ++j) {
    float ax = 0.f, ay = 0.f, az = 0.f, aw = 0.f;
#pragma unroll
    for (int k = 0; k < 8; ++k) {
      float4 vv = *(const float4*)&Vs[h * 260 + k * 32 + 4 * j];
      ax = fmaf(sc[k], vv.x, ax);
      ay = fmaf(sc[k], vv.y, ay);
      az = fmaf(sc[k], vv.z, az);
      aw = fmaf(sc[k], vv.w, aw);
    }
    f16x4v o16 = {f2h(ax * inv), f2h(ay * inv), f2h(az * inv), f2h(aw * inv)};
    *(f16x4v*)&O16[(size_t)(n * VV + qi) * DD + h * DKK + 4 * j] = o16;
  }
}

// ---------------- LN helpers -----------------------------------------------
__global__ __launch_bounds__(256) void k_ln_double(
    const float* __restrict__ T, const float* __restrict__ g1,
    const float* __restrict__ c1, const float* __restrict__ g2,
    const float* __restrict__ c2, float* __restrict__ Ev,
    _Float16* __restrict__ Ev16) {
  int r = blockIdx.x * 4 + (threadIdx.x >> 6);
  int lane = threadIdx.x & 63;
  float4 xv = ((const float4*)T)[r * 64 + lane];
  float sum = xv.x + xv.y + xv.z + xv.w;
  float sq = fmaf(xv.x, xv.x, fmaf(xv.y, xv.y, fmaf(xv.z, xv.z, xv.w * xv.w)));
#pragma unroll
  for (int off = 32; off > 0; off >>= 1) {
    sum += __shfl_xor(sum, off);
    sq += __shfl_xor(sq, off);
  }
  float mean = sum * (1.0f / 256.0f);
  float var = sq * (1.0f / 256.0f) - mean * mean;
  float rstd = rsqrtf(var + LN_EPS);
  float4 gg = ((const float4*)g1)[lane];
  float4 bb = ((const float4*)c1)[lane];
  float4 z;
  z.x = fmaf((xv.x - mean) * rstd, gg.x, bb.x);
  z.y = fmaf((xv.y - mean) * rstd, gg.y, bb.y);
  z.z = fmaf((xv.z - mean) * rstd, gg.z, bb.z);
  z.w = fmaf((xv.w - mean) * rstd, gg.w, bb.w);
  float sum2 = z.x + z.y + z.z + z.w;
  float sq2 = fmaf(z.x, z.x, fmaf(z.y, z.y, fmaf(z.z, z.z, z.w * z.w)));
#pragma unroll
  for (int off = 32; off > 0; off >>= 1) {
    sum2 += __shfl_xor(sum2, off);
    sq2 += __shfl_xor(sq2, off);
  }
  float mean2 = sum2 * (1.0f / 256.0f);
  float var2 = sq2 * (1.0f / 256.0f) - mean2 * mean2;
  float rstd2 = rsqrtf(var2 + LN_EPS);
  float4 g2v = ((const float4*)g2)[lane];
  float4 b2v = ((const float4*)c2)[lane];
  float4 w;
  w.x = fmaf((z.x - mean2) * rstd2, g2v.x, b2v.x);
  w.y = fmaf((z.y - mean2) * rstd2, g2v.y, b2v.y);
  w.z = fmaf((z.z - mean2) * rstd2, g2v.z, b2v.z);
  w.w = fmaf((z.w - mean2) * rstd2, g2v.w, b2v.w);
  int n = r / SS;
  int sidx = r - n * SS;
  int b = n >> 3, v = n & 7;
  int r2 = (b * SS + sidx) * VV + v;
  ((float4*)Ev)[r2 * 64 + lane] = w;
  f16x4v h16 = {f2h(w.x), f2h(w.y), f2h(w.z), f2h(w.w)};
  *(f16x4v*)&Ev16[(size_t)r2 * 256 + lane * 4] = h16;
}

__global__ __launch_bounds__(256) void k_ln_single(
    const float* __restrict__ T, const float* __restrict__ g1,
    const float* __restrict__ c1, float* __restrict__ Et,
    _Float16* __restrict__ Et16) {
  int r = blockIdx.x * 4 + (threadIdx.x >> 6);
  int lane = threadIdx.x & 63;
  float4 xv = ((const float4*)T)[r * 64 + lane];
  float sum = xv.x + xv.y + xv.z + xv.w;
  float sq = fmaf(xv.x, xv.x, fmaf(xv.y, xv.y, fmaf(xv.z, xv.z, xv.w * xv.w)));
#pragma unroll
  for (int off = 32; off > 0; off >>= 1) {
    sum += __shfl_xor(sum, off);
    sq += __shfl_xor(sq, off);
  }
  float mean = sum * (1.0f / 256.0f);
  float var = sq * (1.0f / 256.0f) - mean * mean;
  float rstd = rsqrtf(var + LN_EPS);
  float4 gg = ((const float4*)g1)[lane];
  float4 bb = ((const float4*)c1)[lane];
  float4 w;
  w.x = fmaf((xv.x - mean) * rstd, gg.x, bb.x);
  w.y = fmaf((xv.y - mean) * rstd, gg.y, bb.y);
  w.z = fmaf((xv.z - mean) * rstd, gg.z, bb.z);
  w.w = fmaf((xv.w - mean) * rstd, gg.w, bb.w);
  int t = r >> 3;
  int v = r & 7;
  int b = t / SS;
  int sidx = t - b * SS;
  int r2 = (b * VV + v) * SS + sidx;
  ((float4*)Et)[r2 * 64 + lane] = w;
  f16x4v h16 = {f2h(w.x), f2h(w.y), f2h(w.z), f2h(w.w)};
  *(f16x4v*)&Et16[(size_t)r2 * 256 + lane * 4] = h16;
}

// ---------------- final projection -----------------------------------------
__global__ __launch_bounds__(192) void k_proj_partial(
    const float* __restrict__ E, const float* __restrict__ PW,
    float* __restrict__ Part) {
  int kc = blockIdx.x;
  int tid = threadIdx.x;
  int p4 = tid % 24, g = tid / 24;
  __shared__ float Es[16][128];
  __shared__ float sm[8][1536];
  for (int idx = tid; idx < 512; idx += 192) {   // 16 rows * 32 float4
    int row = idx >> 5, kk4 = idx & 31;
    *(float4*)&Es[row][kk4 * 4] =
        *(const float4*)&E[(size_t)row * 86016 + kc * 128 + kk4 * 4];
  }
  __syncthreads();
  float4 acc[16];
#pragma unroll
  for (int i = 0; i < 16; ++i) acc[i] = make_float4(0.f, 0.f, 0.f, 0.f);
  for (int j = 0; j < 16; ++j) {
    int k = g * 16 + j;
    float4 w = *(const float4*)&PW[(size_t)(kc * 128 + k) * 96 + p4 * 4];
#pragma unroll
    for (int row = 0; row < 16; ++row) {
      float e = Es[row][k];
      acc[row].x = fmaf(e, w.x, acc[row].x);
      acc[row].y = fmaf(e, w.y, acc[row].y);
      acc[row].z = fmaf(e, w.z, acc[row].z);
      acc[row].w = fmaf(e, w.w, acc[row].w);
    }
  }
#pragma unroll
  for (int row = 0; row < 16; ++row)
    *(float4*)&sm[g][row * 96 + p4 * 4] = acc[row];
  __syncthreads();
  for (int o = tid; o < 1536; o += 192) {   // o = row*96 + p
    float s = 0.f;
#pragma unroll
    for (int g2 = 0; g2 < 8; ++g2) s += sm[g2][o];
    Part[(size_t)kc * 1536 + o] = s;
  }
}

__global__ __launch_bounds__(256) void k_proj_reduce1(
    const float* __restrict__ Part, float* __restrict__ out2) {
  int blk = blockIdx.x;               // 48 = 8 cb * 6 ib
  int cb = blk / 6, ib = blk % 6;
  int i = ib * 256 + threadIdx.x;     // i = row*96 + p
  float s = 0.f;
  for (int c = cb * 84; c < cb * 84 + 84; ++c) s += Part[(size_t)c * 1536 + i];
  out2[cb * 1536 + i] = s;
}

__global__ __launch_bounds__(256) void k_proj_reduce2(
    const float* __restrict__ out2, const float* __restrict__ PB,
    float* __restrict__ out) {
  int j = blockIdx.x * 256 + threadIdx.x;   // j = row*96 + p
  int row = j / 96, p = j - row * 96;
  float s = PB[p];
#pragma unroll
  for (int cb = 0; cb < 8; ++cb) s += out2[cb * 1536 + j];
  int b = row >> 3, v = row & 7;
  out[b * 768 + p * 8 + v] = s;
}

// ---------------- launch ---------------------------------------------------
extern "C" void kernel_launch(void* const* d_in, const int* in_sizes, int n_in,
                              void* d_out, int out_size, void* d_ws,
                              size_t ws_size, hipStream_t stream) {
  const float* x     = (const float*)d_in[0];
  const float* emb_w = (const float*)d_in[1];
  const float* emb_b = (const float*)d_in[2];
  const float* Wq = (const float*)d_in[3];
  const float* bq = (const float*)d_in[4];
  const float* Wk = (const float*)d_in[5];
  const float* bk = (const float*)d_in[6];
  const float* Wv = (const float*)d_in[7];
  const float* bv = (const float*)d_in[8];
  const float* Wo = (const float*)d_in[9];
  const float* bo = (const float*)d_in[10];
  const float* g1 = (const float*)d_in[11];
  const float* b1 = (const float*)d_in[12];
  const float* gn = (const float*)d_in[13];
  const float* bn = (const float*)d_in[14];
  const float* PW = (const float*)d_in[15];
  const float* PB = (const float*)d_in[16];
  float* out = (float*)d_out;

  float* ws = (float*)d_ws;
  float* Etime = ws;                          // NTD fp32
  float* Evar  = ws + (size_t)NTD;            // NTD fp32
  _Float16* Q16 = (_Float16*)(ws + 2 * (size_t)NTD);
  _Float16* K16 = Q16 + (size_t)NTD;
  _Float16* V16 = (_Float16*)(ws + 3 * (size_t)NTD);
  _Float16* AO16 = V16 + (size_t)NTD;
  float* T1 = ws + 4 * (size_t)NTD;           // fp32; reused as Part post-loop
  _Float16* Et16 = (_Float16*)(ws + 5 * (size_t)NTD);
  _Float16* Ev16 = Et16 + (size_t)NTD;
  _Float16* WT = (_Float16*)(ws + 6 * (size_t)NTD);   // 4*65536 f16
  float* Part = T1;
  float* out2 = ws + 6 * (size_t)NTD + 131072;        // after WT

  k_prep_w<<<dim3(256, 4), 256, 0, stream>>>(Wq, Wk, Wv, Wo, WT);
  k_embed<<<NTOK, 256, 0, stream>>>(x, emb_w, emb_b, Etime, Et16);
  for (int it = 0; it < 10; ++it) {
    // ---- attention over time axis (N=16, L=336) ----
    k_gemm_f16<<<dim3(42, 2, 3), 256, 0, stream>>>(
        Et16, WT, WT + 65536, WT + 2 * 65536, bq, bk, bv,
        Q16, K16, V16, nullptr, nullptr);
    k_attn_time<<<dim3(6, 8, 16), 256, 0, stream>>>(Q16, K16, V16, AO16);
    k_gemm_f16<<<dim3(42, 2, 1), 256, 0, stream>>>(
        AO16, WT + 3 * 65536, WT + 3 * 65536, WT + 3 * 65536, bo, bo, bo,
        nullptr, nullptr, nullptr, T1, Etime);
    k_ln_double<<<NTOK / 4, 256, 0, stream>>>(T1, g1, b1, gn, bn, Evar, Ev16);
    // ---- attention over variable axis (N=672, L=8) ----
    k_gemm_f16<<<dim3(42, 2, 3), 256, 0, stream>>>(
        Ev16, WT, WT + 65536, WT + 2 * 65536, bq, bk, bv,
        Q16, K16, V16, nullptr, nullptr);
    k_attn_var<<<672, 64, 0, stream>>>(Q16, K16, V16, AO16);
    k_gemm_f16<<<dim3(42, 2, 1), 256, 0, stream>>>(
        AO16, WT + 3 * 65536, WT + 3 * 65536, WT + 3 * 65536, bo, bo, bo,
        nullptr, nullptr, nullptr, T1, Evar);
    k_ln_single<<<NTOK / 4, 256, 0, stream>>>(T1, g1, b1, Etime, Et16);
  }
  k_proj_partial<<<672, 192, 0, stream>>>(Etime, PW, Part);
  k_proj_reduce1<<<48, 256, 0, stream>>>(Part, out2);
  k_proj_reduce2<<<6, 256, 0, stream>>>(out2, PB, out);
}

// Round 6
// 869.983 us; speedup vs baseline: 2.5980x; 1.3962x over previous
//
#include <hip/hip_runtime.h>

#define SS 336
#define VV 8
#define DD 256
#define DKK 32
#define NTOK 5376            // B*V*S = B*S*V tokens
#define NTD (NTOK * DD)      // 1376256 elements per activation buffer
#define ATT_SCALE 0.17677669529663687f  // 1/sqrt(32)
#define LN_EPS 1e-5f

typedef _Float16 f16x8 __attribute__((ext_vector_type(8)));
typedef _Float16 f16x4v __attribute__((ext_vector_type(4)));
typedef __attribute__((ext_vector_type(4))) float f32x4;

__device__ inline _Float16 f2h(float f) { return (_Float16)f; }

// ---------------- weight prep: WT[z][n][k] = f16(W_z[k][n]) ----------------
__global__ __launch_bounds__(256) void k_prep_w(
    const float* __restrict__ Wq, const float* __restrict__ Wk,
    const float* __restrict__ Wv, const float* __restrict__ Wo,
    _Float16* __restrict__ WT) {
  int z = blockIdx.y;
  const float* W = (z == 0) ? Wq : (z == 1) ? Wk : (z == 2) ? Wv : Wo;
  int o = blockIdx.x * 256 + threadIdx.x;   // 65536 per matrix
  int n = o >> 8, k = o & 255;
  WT[z * 65536 + n * 256 + k] = f2h(W[k * 256 + n]);
}

// ---------------- embed ----------------------------------------------------
__global__ __launch_bounds__(256) void k_embed(
    const float* __restrict__ x, const float* __restrict__ ew,
    const float* __restrict__ eb, float* __restrict__ E,
    _Float16* __restrict__ E16) {
  int token = blockIdx.x;            // (b*V+v)*S + s
  int n = token / SS, s = token - n * SS;
  int b = n >> 3, v = n & 7;
  float xv = x[(b * SS + s) * VV + v];
  int d = threadIdx.x;
  float val = fmaf(xv, ew[d], eb[d]);
  E[token * DD + d] = val;
  E16[token * DD + d] = f2h(val);
}

// ---------------- QKV GEMM: H_z = A[5376,256] @ Wz + bz  (f16 out) ---------
// grid (84, 2, z); block 256 = 4 waves (2m x 2n); 64x128 tile; BK=32.
__global__ __launch_bounds__(256) void k_gemm_qkv(
    const _Float16* __restrict__ A16,
    const _Float16* __restrict__ wt0, const _Float16* __restrict__ wt1,
    const _Float16* __restrict__ wt2,
    const float* __restrict__ c0, const float* __restrict__ c1,
    const float* __restrict__ c2,
    _Float16* __restrict__ H0, _Float16* __restrict__ H1,
    _Float16* __restrict__ H2) {
  int z = blockIdx.z;
  const _Float16* WT = (z == 0) ? wt0 : (z == 1) ? wt1 : wt2;
  const float* bias  = (z == 0) ? c0 : (z == 1) ? c1 : c2;
  _Float16* H        = (z == 0) ? H0 : (z == 1) ? H1 : H2;
  int m0 = blockIdx.x * 64, n0 = blockIdx.y * 128;
  int tid = threadIdx.x;
  int wave = tid >> 6, lane = tid & 63;
  int wm = wave >> 1, wn = wave & 1;
  int quad = lane >> 4, lcol = lane & 15;

  __shared__ _Float16 As[4 * 64 * 8];    // [kseg][row][8]
  __shared__ _Float16 Bs[4 * 128 * 8];

  f32x4 acc[2][4] = {};

  for (int k0 = 0; k0 < 256; k0 += 32) {
    __syncthreads();
    {
      int row = tid >> 2, ks = tid & 3;
      *(f16x8*)&As[(ks * 64 + row) * 8] =
          *(const f16x8*)&A16[(size_t)(m0 + row) * 256 + k0 + ks * 8];
    }
#pragma unroll
    for (int p = 0; p < 2; ++p) {
      int c = tid + p * 256;
      int row = c >> 2, ks = c & 3;
      *(f16x8*)&Bs[(ks * 128 + row) * 8] =
          *(const f16x8*)&WT[(size_t)(n0 + row) * 256 + k0 + ks * 8];
    }
    __syncthreads();
    f16x8 af[2], bfr[4];
#pragma unroll
    for (int mt = 0; mt < 2; ++mt)
      af[mt] = *(const f16x8*)&As[(quad * 64 + wm * 32 + mt * 16 + lcol) * 8];
#pragma unroll
    for (int nt = 0; nt < 4; ++nt)
      bfr[nt] = *(const f16x8*)&Bs[(quad * 128 + wn * 64 + nt * 16 + lcol) * 8];
#pragma unroll
    for (int mt = 0; mt < 2; ++mt)
#pragma unroll
      for (int nt = 0; nt < 4; ++nt)
        acc[mt][nt] = __builtin_amdgcn_mfma_f32_16x16x32_f16(
            af[mt], bfr[nt], acc[mt][nt], 0, 0, 0);
  }

  float bsv[4];
#pragma unroll
  for (int nt = 0; nt < 4; ++nt) bsv[nt] = bias[n0 + wn * 64 + nt * 16 + lcol];
#pragma unroll
  for (int mt = 0; mt < 2; ++mt) {
#pragma unroll
    for (int i = 0; i < 4; ++i) {
      int r = m0 + wm * 32 + mt * 16 + quad * 4 + i;
#pragma unroll
      for (int nt = 0; nt < 4; ++nt) {
        int c = n0 + wn * 64 + nt * 16 + lcol;
        H[(size_t)r * 256 + c] = f2h(acc[mt][nt][i] + bsv[nt]);
      }
    }
  }
}

// ---------------- fused O-proj + bias + residual + LN(x1/2) + permute ------
// grid 84, block 256 = 4 waves; wave handles 16 rows x 256 cols, K=256.
// dbl: apply second LN (gn,bn). mode 0: time->var permute; 1: var->time.
__global__ __launch_bounds__(256) void k_oproj_ln(
    const _Float16* __restrict__ A16, const _Float16* __restrict__ WT,
    const float* __restrict__ bo, const float* __restrict__ Res,
    const float* __restrict__ g1, const float* __restrict__ c1,
    const float* __restrict__ g2, const float* __restrict__ c2,
    int dbl, int mode, float* __restrict__ Ef, _Float16* __restrict__ E16) {
  int m0 = blockIdx.x * 64;
  int tid = threadIdx.x;
  int wave = tid >> 6, lane = tid & 63;
  int quad = lane >> 4, lcol = lane & 15;

  __shared__ _Float16 As[4 * 64 * 8];     // 4 KB
  __shared__ _Float16 Bs[4 * 256 * 8];    // 16 KB
  __shared__ float Cb[64 * 260];          // 66.6 KB, padded stride

  f32x4 acc[16] = {};

  for (int k0 = 0; k0 < 256; k0 += 32) {
    __syncthreads();
    {
      int row = tid >> 2, ks = tid & 3;
      *(f16x8*)&As[(ks * 64 + row) * 8] =
          *(const f16x8*)&A16[(size_t)(m0 + row) * 256 + k0 + ks * 8];
    }
#pragma unroll
    for (int p = 0; p < 4; ++p) {
      int c = tid + p * 256;
      int row = c >> 2, ks = c & 3;
      *(f16x8*)&Bs[(ks * 256 + row) * 8] =
          *(const f16x8*)&WT[(size_t)row * 256 + k0 + ks * 8];
    }
    __syncthreads();
    f16x8 af = *(const f16x8*)&As[(quad * 64 + wave * 16 + lcol) * 8];
#pragma unroll
    for (int nt = 0; nt < 16; ++nt) {
      f16x8 bfr = *(const f16x8*)&Bs[(quad * 256 + nt * 16 + lcol) * 8];
      acc[nt] = __builtin_amdgcn_mfma_f32_16x16x32_f16(af, bfr, acc[nt], 0, 0, 0);
    }
  }

  // bias + residual (fp32)
#pragma unroll
  for (int nt = 0; nt < 16; ++nt) {
    int col = nt * 16 + lcol;
    float bv = bo[col];
#pragma unroll
    for (int i = 0; i < 4; ++i) {
      int r = m0 + wave * 16 + quad * 4 + i;
      acc[nt][i] += bv + Res[(size_t)r * 256 + col];
    }
  }

  // LN 1 (and optionally LN 2), rows = quad*4+i within the wave's 16
  for (int pass = 0; pass < 1 + dbl; ++pass) {
    const float* gg = (pass == 0) ? g1 : g2;
    const float* bb = (pass == 0) ? c1 : c2;
    float mu[4], rs[4];
#pragma unroll
    for (int i = 0; i < 4; ++i) {
      float s = 0.f, q = 0.f;
#pragma unroll
      for (int nt = 0; nt < 16; ++nt) {
        float v = acc[nt][i];
        s += v;
        q = fmaf(v, v, q);
      }
#pragma unroll
      for (int off = 8; off > 0; off >>= 1) {
        s += __shfl_xor(s, off);
        q += __shfl_xor(q, off);
      }
      mu[i] = s * (1.0f / 256.0f);
      float var = q * (1.0f / 256.0f) - mu[i] * mu[i];
      rs[i] = rsqrtf(var + LN_EPS);
    }
#pragma unroll
    for (int nt = 0; nt < 16; ++nt) {
      int col = nt * 16 + lcol;
      float g = gg[col], b = bb[col];
#pragma unroll
      for (int i = 0; i < 4; ++i)
        acc[nt][i] = fmaf((acc[nt][i] - mu[i]) * rs[i], g, b);
    }
  }

  // stage to LDS for coalesced permuted stores
#pragma unroll
  for (int nt = 0; nt < 16; ++nt) {
#pragma unroll
    for (int i = 0; i < 4; ++i)
      Cb[(wave * 16 + quad * 4 + i) * 260 + nt * 16 + lcol] = acc[nt][i];
  }
  __syncthreads();

#pragma unroll
  for (int t = 0; t < 16; ++t) {
    int o = tid + t * 256;          // 64 rows * 64 col4
    int row = o >> 6, c4 = o & 63;
    int r = m0 + row;
    int r2;
    if (mode == 0) {                // (b*V+v)*S+s -> (b*S+s)*V+v
      int n = r / SS, sidx = r - n * SS;
      int b = n >> 3, v = n & 7;
      r2 = (b * SS + sidx) * VV + v;
    } else {                        // (b*S+s)*V+v -> (b*V+v)*S+s
      int tt = r >> 3, v = r & 7;
      int b = tt / SS, sidx = tt - b * SS;
      r2 = (b * VV + v) * SS + sidx;
    }
    float4 val = *(const float4*)&Cb[row * 260 + c4 * 4];
    *(float4*)&Ef[(size_t)r2 * 256 + c4 * 4] = val;
    f16x4v h16 = {f2h(val.x), f2h(val.y), f2h(val.z), f2h(val.w)};
    *(f16x4v*)&E16[(size_t)r2 * 256 + c4 * 4] = h16;
  }
}

// ---------------- time attention: MFMA flash, f16 in/out -------------------
#define KSTR 36
#define VTSTR 344
__global__ __launch_bounds__(256) void k_attn_time(
    const _Float16* __restrict__ Q, const _Float16* __restrict__ K,
    const _Float16* __restrict__ V, _Float16* __restrict__ O16) {
  int qg = blockIdx.x, h = blockIdx.y, n = blockIdx.z;
  int tid = threadIdx.x;
  int wave = tid >> 6, lane = tid & 63;
  int quad = lane >> 4, lcol = lane & 15;

  __shared__ _Float16 Ks[336 * KSTR];
  __shared__ _Float16 Vt[32 * VTSTR + 16];
  __shared__ _Float16 Ps[4][16 * 40];

  const size_t base = (size_t)(n * SS) * DD + h * DKK;

  for (int c = tid; c < 1344; c += 256) {
    int row = c >> 2, part = c & 3;
    f16x8 kv = *(const f16x8*)&K[base + (size_t)row * DD + part * 8];
    f16x4v klo = __builtin_shufflevector(kv, kv, 0, 1, 2, 3);
    f16x4v khi = __builtin_shufflevector(kv, kv, 4, 5, 6, 7);
    *(f16x4v*)&Ks[row * KSTR + part * 8] = klo;
    *(f16x4v*)&Ks[row * KSTR + part * 8 + 4] = khi;
    f16x8 vv = *(const f16x8*)&V[base + (size_t)row * DD + part * 8];
#pragma unroll
    for (int j = 0; j < 8; ++j) Vt[(part * 8 + j) * VTSTR + row] = vv[j];
  }
  for (int c = tid; c < 272; c += 256) {
    if (c < 256) {
      int d = c >> 3, col = 336 + (c & 7);
      Vt[d * VTSTR + col] = (_Float16)0.f;
    } else {
      Vt[32 * VTSTR + (c - 256)] = (_Float16)0.f;
    }
  }
  __syncthreads();

  int qtile = qg * 4 + wave;
  if (qtile >= 21) return;
  int qb = qtile * 16;

  f16x8 qf = *(const f16x8*)&Q[base + (size_t)(qb + lcol) * DD + quad * 8];
  f32x4 accA = {0.f, 0.f, 0.f, 0.f};
  f32x4 accB = {0.f, 0.f, 0.f, 0.f};
  f32x4 lacc = {0.f, 0.f, 0.f, 0.f};
  float m_[4] = {-1e30f, -1e30f, -1e30f, -1e30f};
  _Float16* P = Ps[wave];
  const f16x8 onesv = {(_Float16)1.f, (_Float16)1.f, (_Float16)1.f, (_Float16)1.f,
                       (_Float16)1.f, (_Float16)1.f, (_Float16)1.f, (_Float16)1.f};
  const f32x4 z4 = {0.f, 0.f, 0.f, 0.f};

  for (int t = 0; t < 11; ++t) {
    int k0 = t * 32;
    bool full = (t < 10);
    const _Float16* kp0 = &Ks[(k0 + lcol) * KSTR + quad * 8];
    f16x4v ka = *(const f16x4v*)kp0;
    f16x4v kb = *(const f16x4v*)(kp0 + 4);
    f16x8 kf0 = __builtin_shufflevector(ka, kb, 0, 1, 2, 3, 4, 5, 6, 7);
    f32x4 s0 = __builtin_amdgcn_mfma_f32_16x16x32_f16(qf, kf0, z4, 0, 0, 0);
    f32x4 s1 = z4;
    if (full) {
      const _Float16* kp1 = &Ks[(k0 + 16 + lcol) * KSTR + quad * 8];
      f16x4v ka1 = *(const f16x4v*)kp1;
      f16x4v kb1 = *(const f16x4v*)(kp1 + 4);
      f16x8 kf1 = __builtin_shufflevector(ka1, kb1, 0, 1, 2, 3, 4, 5, 6, 7);
      s1 = __builtin_amdgcn_mfma_f32_16x16x32_f16(qf, kf1, z4, 0, 0, 0);
    }
    float sc0[4], sc1[4], p0[4], p1[4], corr[4];
#pragma unroll
    for (int i = 0; i < 4; ++i) {
      sc0[i] = s0[i] * ATT_SCALE;
      sc1[i] = full ? s1[i] * ATT_SCALE : -1e30f;
    }
#pragma unroll
    for (int i = 0; i < 4; ++i) {
      float t2 = fmaxf(sc0[i], sc1[i]);
      t2 = fmaxf(t2, __shfl_xor(t2, 1));
      t2 = fmaxf(t2, __shfl_xor(t2, 2));
      t2 = fmaxf(t2, __shfl_xor(t2, 4));
      t2 = fmaxf(t2, __shfl_xor(t2, 8));
      float nm = fmaxf(m_[i], t2);
      corr[i] = __expf(m_[i] - nm);
      m_[i] = nm;
      p0[i] = __expf(sc0[i] - nm);
      p1[i] = __expf(sc1[i] - nm);
      accA[i] *= corr[i];
      accB[i] *= corr[i];
      lacc[i] *= corr[i];
    }
#pragma unroll
    for (int i = 0; i < 4; ++i) {
      P[(quad * 4 + i) * 40 + lcol] = f2h(p0[i]);
      P[(quad * 4 + i) * 40 + 16 + lcol] = f2h(p1[i]);
    }
    f16x8 pf = *(const f16x8*)&P[lcol * 40 + quad * 8];
    lacc = __builtin_amdgcn_mfma_f32_16x16x32_f16(pf, onesv, lacc, 0, 0, 0);
    f16x8 vb0 = *(const f16x8*)&Vt[lcol * VTSTR + k0 + quad * 8];
    f16x8 vb1 = *(const f16x8*)&Vt[(16 + lcol) * VTSTR + k0 + quad * 8];
    accA = __builtin_amdgcn_mfma_f32_16x16x32_f16(pf, vb0, accA, 0, 0, 0);
    accB = __builtin_amdgcn_mfma_f32_16x16x32_f16(pf, vb1, accB, 0, 0, 0);
  }

#pragma unroll
  for (int i = 0; i < 4; ++i) {
    float inv = 1.f / lacc[i];
    P[(quad * 4 + i) * 40 + lcol] = f2h(accA[i] * inv);
    P[(quad * 4 + i) * 40 + 16 + lcol] = f2h(accB[i] * inv);
  }
  int row = lane >> 2, seg = lane & 3;
  f16x8 ov = *(const f16x8*)&P[row * 40 + seg * 8];
  *(f16x8*)&O16[base + (size_t)(qb + row) * DD + seg * 8] = ov;
}

// ---------------- variable attention: N=672, L=8, f16 in/out ---------------
__global__ __launch_bounds__(64) void k_attn_var(
    const _Float16* __restrict__ Q, const _Float16* __restrict__ K,
    const _Float16* __restrict__ V, _Float16* __restrict__ O16) {
  int n = blockIdx.x;
  int tid = threadIdx.x;
  __shared__ float Ks[2080];
  __shared__ float Vs[2080];
  for (int f = tid; f < 256; f += 64) {
    int l = f >> 5, c8 = f & 31, hh = c8 >> 2, j8 = c8 & 3;
    f16x8 kv = *(const f16x8*)&K[(size_t)(n * VV + l) * DD + c8 * 8];
    f16x8 vv = *(const f16x8*)&V[(size_t)(n * VV + l) * DD + c8 * 8];
    float* kd = &Ks[hh * 260 + l * 32 + j8 * 8];
    float* vd = &Vs[hh * 260 + l * 32 + j8 * 8];
#pragma unroll
    for (int j = 0; j < 8; ++j) {
      kd[j] = (float)kv[j];
      vd[j] = (float)vv[j];
    }
  }
  __syncthreads();
  int h = tid >> 3, qi = tid & 7;
  float4 q4[8];
  const _Float16* qp = &Q[(size_t)(n * VV + qi) * DD + h * DKK];
#pragma unroll
  for (int j4 = 0; j4 < 4; ++j4) {
    f16x8 qv = *(const f16x8*)&qp[j4 * 8];
    q4[2 * j4] = make_float4((float)qv[0], (float)qv[1], (float)qv[2], (float)qv[3]);
    q4[2 * j4 + 1] = make_float4((float)qv[4], (float)qv[5], (float)qv[6], (float)qv[7]);
  }
  float sc[8];
#pragma unroll
  for (int k = 0; k < 8; ++k) {
    const float4* krow = (const float4*)&Ks[h * 260 + k * 32];
    float s0 = 0.f, s1 = 0.f, s2 = 0.f, s3 = 0.f;
#pragma unroll
    for (int j = 0; j < 8; ++j) {
      float4 kv = krow[j];
      s0 = fmaf(q4[j].x, kv.x, s0);
      s1 = fmaf(q4[j].y, kv.y, s1);
      s2 = fmaf(q4[j].z, kv.z, s2);
      s3 = fmaf(q4[j].w, kv.w, s3);
    }
    sc[k] = ((s0 + s1) + (s2 + s3)) * ATT_SCALE;
  }
  float mx = sc[0];
#pragma unroll
  for (int k = 1; k < 8; ++k) mx = fmaxf(mx, sc[k]);
  float psum = 0.f;
#pragma unroll
  for (int k = 0; k < 8; ++k) {
    sc[k] = __expf(sc[k] - mx);
    psum += sc[k];
  }
  float inv = 1.f / psum;
#pragma unroll
  for (int j = 0; j < 8; ++j) {
    float ax = 0.f, ay = 0.f, az = 0.f, aw = 0.f;
#pragma unroll
    for (int k = 0; k < 8; ++k) {
      float4 vv = *(const float4*)&Vs[h * 260 + k * 32 + 4 * j];
      ax = fmaf(sc[k], vv.x, ax);
      ay = fmaf(sc[k], vv.y, ay);
      az = fmaf(sc[k], vv.z, az);
      aw = fmaf(sc[k], vv.w, aw);
    }
    f16x4v o16 = {f2h(ax * inv), f2h(ay * inv), f2h(az * inv), f2h(aw * inv)};
    *(f16x4v*)&O16[(size_t)(n * VV + qi) * DD + h * DKK + 4 * j] = o16;
  }
}

// ---------------- final projection -----------------------------------------
__global__ __launch_bounds__(192) void k_proj_partial(
    const float* __restrict__ E, const float* __restrict__ PW,
    float* __restrict__ Part) {
  int kc = blockIdx.x;
  int tid = threadIdx.x;
  int p4 = tid % 24, g = tid / 24;
  __shared__ float Es[16][128];
  __shared__ float sm[8][1536];
  for (int idx = tid; idx < 512; idx += 192) {
    int row = idx >> 5, kk4 = idx & 31;
    *(float4*)&Es[row][kk4 * 4] =
        *(const float4*)&E[(size_t)row * 86016 + kc * 128 + kk4 * 4];
  }
  __syncthreads();
  float4 acc[16];
#pragma unroll
  for (int i = 0; i < 16; ++i) acc[i] = make_float4(0.f, 0.f, 0.f, 0.f);
  for (int j = 0; j < 16; ++j) {
    int k = g * 16 + j;
    float4 w = *(const float4*)&PW[(size_t)(kc * 128 + k) * 96 + p4 * 4];
#pragma unroll
    for (int row = 0; row < 16; ++row) {
      float e = Es[row][k];
      acc[row].x = fmaf(e, w.x, acc[row].x);
      acc[row].y = fmaf(e, w.y, acc[row].y);
      acc[row].z = fmaf(e, w.z, acc[row].z);
      acc[row].w = fmaf(e, w.w, acc[row].w);
    }
  }
#pragma unroll
  for (int row = 0; row < 16; ++row)
    *(float4*)&sm[g][row * 96 + p4 * 4] = acc[row];
  __syncthreads();
  for (int o = tid; o < 1536; o += 192) {
    float s = 0.f;
#pragma unroll
    for (int g2 = 0; g2 < 8; ++g2) s += sm[g2][o];
    Part[(size_t)kc * 1536 + o] = s;
  }
}

__global__ __launch_bounds__(256) void k_proj_reduce1(
    const float* __restrict__ Part, float* __restrict__ out2) {
  int blk = blockIdx.x;               // 48 = 8 cb * 6 ib
  int cb = blk / 6, ib = blk % 6;
  int i = ib * 256 + threadIdx.x;
  float s = 0.f;
  for (int c = cb * 84; c < cb * 84 + 84; ++c) s += Part[(size_t)c * 1536 + i];
  out2[cb * 1536 + i] = s;
}

__global__ __launch_bounds__(256) void k_proj_reduce2(
    const float* __restrict__ out2, const float* __restrict__ PB,
    float* __restrict__ out) {
  int j = blockIdx.x * 256 + threadIdx.x;
  int row = j / 96, p = j - row * 96;
  float s = PB[p];
#pragma unroll
  for (int cb = 0; cb < 8; ++cb) s += out2[cb * 1536 + j];
  int b = row >> 3, v = row & 7;
  out[b * 768 + p * 8 + v] = s;
}

// ---------------- launch ---------------------------------------------------
extern "C" void kernel_launch(void* const* d_in, const int* in_sizes, int n_in,
                              void* d_out, int out_size, void* d_ws,
                              size_t ws_size, hipStream_t stream) {
  const float* x     = (const float*)d_in[0];
  const float* emb_w = (const float*)d_in[1];
  const float* emb_b = (const float*)d_in[2];
  const float* Wq = (const float*)d_in[3];
  const float* bq = (const float*)d_in[4];
  const float* Wk = (const float*)d_in[5];
  const float* bk = (const float*)d_in[6];
  const float* Wv = (const float*)d_in[7];
  const float* bv = (const float*)d_in[8];
  const float* Wo = (const float*)d_in[9];
  const float* bo = (const float*)d_in[10];
  const float* g1 = (const float*)d_in[11];
  const float* b1 = (const float*)d_in[12];
  const float* gn = (const float*)d_in[13];
  const float* bn = (const float*)d_in[14];
  const float* PW = (const float*)d_in[15];
  const float* PB = (const float*)d_in[16];
  float* out = (float*)d_out;

  float* ws = (float*)d_ws;
  float* Etime = ws;                          // NTD f32
  float* Evar  = ws + (size_t)NTD;            // NTD f32
  _Float16* Q16  = (_Float16*)(ws + 2 * (size_t)NTD);
  _Float16* K16  = Q16 + (size_t)NTD;
  _Float16* V16  = (_Float16*)(ws + 3 * (size_t)NTD);
  _Float16* AO16 = V16 + (size_t)NTD;
  _Float16* Et16 = (_Float16*)(ws + 4 * (size_t)NTD);
  _Float16* Ev16 = Et16 + (size_t)NTD;
  _Float16* WT   = (_Float16*)(ws + 5 * (size_t)NTD);   // 262144 f16
  float* Part = ws + 5 * (size_t)NTD + 131072;          // 672*1536
  float* out2 = Part + 672 * 1536;                      // 8*1536

  k_prep_w<<<dim3(256, 4), 256, 0, stream>>>(Wq, Wk, Wv, Wo, WT);
  k_embed<<<NTOK, 256, 0, stream>>>(x, emb_w, emb_b, Etime, Et16);
  for (int it = 0; it < 10; ++it) {
    // ---- attention over time axis (N=16, L=336) ----
    k_gemm_qkv<<<dim3(84, 2, 3), 256, 0, stream>>>(
        Et16, WT, WT + 65536, WT + 2 * 65536, bq, bk, bv, Q16, K16, V16);
    k_attn_time<<<dim3(6, 8, 16), 256, 0, stream>>>(Q16, K16, V16, AO16);
    k_oproj_ln<<<84, 256, 0, stream>>>(
        AO16, WT + 3 * 65536, bo, Etime, g1, b1, gn, bn, 1, 0, Evar, Ev16);
    // ---- attention over variable axis (N=672, L=8) ----
    k_gemm_qkv<<<dim3(84, 2, 3), 256, 0, stream>>>(
        Ev16, WT, WT + 65536, WT + 2 * 65536, bq, bk, bv, Q16, K16, V16);
    k_attn_var<<<672, 64, 0, stream>>>(Q16, K16, V16, AO16);
    k_oproj_ln<<<84, 256, 0, stream>>>(
        AO16, WT + 3 * 65536, bo, Evar, g1, b1, g1, b1, 0, 1, Etime, Et16);
  }
  k_proj_partial<<<672, 192, 0, stream>>>(Etime, PW, Part);
  k_proj_reduce1<<<48, 256, 0, stream>>>(Part, out2);
  k_proj_reduce2<<<6, 256, 0, stream>>>(out2, PB, out);
}

// Round 7
// 838.046 us; speedup vs baseline: 2.6970x; 1.0381x over previous
//
#include <hip/hip_runtime.h>

#define SS 336
#define VV 8
#define DD 256
#define DKK 32
#define NTOK 5376            // B*V*S = B*S*V tokens
#define NTD (NTOK * DD)      // 1376256 elements per activation buffer
#define ATT_SCALE 0.17677669529663687f  // 1/sqrt(32)
#define LN_EPS 1e-5f

typedef _Float16 f16x8 __attribute__((ext_vector_type(8)));
typedef _Float16 f16x4v __attribute__((ext_vector_type(4)));
typedef __attribute__((ext_vector_type(4))) float f32x4;

__device__ inline _Float16 f2h(float f) { return (_Float16)f; }

// ---------------- weight prep: WT[z][n][k] = f16(W_z[k][n]) ----------------
__global__ __launch_bounds__(256) void k_prep_w(
    const float* __restrict__ Wq, const float* __restrict__ Wk,
    const float* __restrict__ Wv, const float* __restrict__ Wo,
    _Float16* __restrict__ WT) {
  int z = blockIdx.y;
  const float* W = (z == 0) ? Wq : (z == 1) ? Wk : (z == 2) ? Wv : Wo;
  int o = blockIdx.x * 256 + threadIdx.x;   // 65536 per matrix
  int n = o >> 8, k = o & 255;
  WT[z * 65536 + n * 256 + k] = f2h(W[k * 256 + n]);
}

// ---------------- embed ----------------------------------------------------
__global__ __launch_bounds__(256) void k_embed(
    const float* __restrict__ x, const float* __restrict__ ew,
    const float* __restrict__ eb, float* __restrict__ E,
    _Float16* __restrict__ E16) {
  int token = blockIdx.x;            // (b*V+v)*S + s
  int n = token / SS, s = token - n * SS;
  int b = n >> 3, v = n & 7;
  float xv = x[(b * SS + s) * VV + v];
  int d = threadIdx.x;
  float val = fmaf(xv, ew[d], eb[d]);
  E[token * DD + d] = val;
  E16[token * DD + d] = f2h(val);
}

// ---------------- QKV GEMM (time stage): H_z = A @ Wz + bz  (f16 out) ------
// grid (84, 2, z); block 256 = 4 waves (2m x 2n); 64x128 tile; BK=32.
__global__ __launch_bounds__(256) void k_gemm_qkv(
    const _Float16* __restrict__ A16,
    const _Float16* __restrict__ wt0, const _Float16* __restrict__ wt1,
    const _Float16* __restrict__ wt2,
    const float* __restrict__ c0, const float* __restrict__ c1,
    const float* __restrict__ c2,
    _Float16* __restrict__ H0, _Float16* __restrict__ H1,
    _Float16* __restrict__ H2) {
  int z = blockIdx.z;
  const _Float16* WT = (z == 0) ? wt0 : (z == 1) ? wt1 : wt2;
  const float* bias  = (z == 0) ? c0 : (z == 1) ? c1 : c2;
  _Float16* H        = (z == 0) ? H0 : (z == 1) ? H1 : H2;
  int m0 = blockIdx.x * 64, n0 = blockIdx.y * 128;
  int tid = threadIdx.x;
  int wave = tid >> 6, lane = tid & 63;
  int wm = wave >> 1, wn = wave & 1;
  int quad = lane >> 4, lcol = lane & 15;

  __shared__ _Float16 As[4 * 64 * 8];    // [kseg][row][8]
  __shared__ _Float16 Bs[4 * 128 * 8];

  f32x4 acc[2][4] = {};

  for (int k0 = 0; k0 < 256; k0 += 32) {
    __syncthreads();
    {
      int row = tid >> 2, ks = tid & 3;
      *(f16x8*)&As[(ks * 64 + row) * 8] =
          *(const f16x8*)&A16[(size_t)(m0 + row) * 256 + k0 + ks * 8];
    }
#pragma unroll
    for (int p = 0; p < 2; ++p) {
      int c = tid + p * 256;
      int row = c >> 2, ks = c & 3;
      *(f16x8*)&Bs[(ks * 128 + row) * 8] =
          *(const f16x8*)&WT[(size_t)(n0 + row) * 256 + k0 + ks * 8];
    }
    __syncthreads();
    f16x8 af[2], bfr[4];
#pragma unroll
    for (int mt = 0; mt < 2; ++mt)
      af[mt] = *(const f16x8*)&As[(quad * 64 + wm * 32 + mt * 16 + lcol) * 8];
#pragma unroll
    for (int nt = 0; nt < 4; ++nt)
      bfr[nt] = *(const f16x8*)&Bs[(quad * 128 + wn * 64 + nt * 16 + lcol) * 8];
#pragma unroll
    for (int mt = 0; mt < 2; ++mt)
#pragma unroll
      for (int nt = 0; nt < 4; ++nt)
        acc[mt][nt] = __builtin_amdgcn_mfma_f32_16x16x32_f16(
            af[mt], bfr[nt], acc[mt][nt], 0, 0, 0);
  }

  float bsv[4];
#pragma unroll
  for (int nt = 0; nt < 4; ++nt) bsv[nt] = bias[n0 + wn * 64 + nt * 16 + lcol];
#pragma unroll
  for (int mt = 0; mt < 2; ++mt) {
#pragma unroll
    for (int i = 0; i < 4; ++i) {
      int r = m0 + wm * 32 + mt * 16 + quad * 4 + i;
#pragma unroll
      for (int nt = 0; nt < 4; ++nt) {
        int c = n0 + wn * 64 + nt * 16 + lcol;
        H[(size_t)r * 256 + c] = f2h(acc[mt][nt][i] + bsv[nt]);
      }
    }
  }
}

// ---------------- time attention: MFMA flash, f16 in/out -------------------
#define KSTR 36
#define VTSTR 344
__global__ __launch_bounds__(256) void k_attn_time(
    const _Float16* __restrict__ Q, const _Float16* __restrict__ K,
    const _Float16* __restrict__ V, _Float16* __restrict__ O16) {
  int qg = blockIdx.x, h = blockIdx.y, n = blockIdx.z;
  int tid = threadIdx.x;
  int wave = tid >> 6, lane = tid & 63;
  int quad = lane >> 4, lcol = lane & 15;

  __shared__ _Float16 Ks[336 * KSTR];
  __shared__ _Float16 Vt[32 * VTSTR + 16];
  __shared__ _Float16 Ps[4][16 * 40];

  const size_t base = (size_t)(n * SS) * DD + h * DKK;

  for (int c = tid; c < 1344; c += 256) {
    int row = c >> 2, part = c & 3;
    f16x8 kv = *(const f16x8*)&K[base + (size_t)row * DD + part * 8];
    f16x4v klo = __builtin_shufflevector(kv, kv, 0, 1, 2, 3);
    f16x4v khi = __builtin_shufflevector(kv, kv, 4, 5, 6, 7);
    *(f16x4v*)&Ks[row * KSTR + part * 8] = klo;
    *(f16x4v*)&Ks[row * KSTR + part * 8 + 4] = khi;
    f16x8 vv = *(const f16x8*)&V[base + (size_t)row * DD + part * 8];
#pragma unroll
    for (int j = 0; j < 8; ++j) Vt[(part * 8 + j) * VTSTR + row] = vv[j];
  }
  for (int c = tid; c < 272; c += 256) {
    if (c < 256) {
      int d = c >> 3, col = 336 + (c & 7);
      Vt[d * VTSTR + col] = (_Float16)0.f;
    } else {
      Vt[32 * VTSTR + (c - 256)] = (_Float16)0.f;
    }
  }
  __syncthreads();

  int qtile = qg * 4 + wave;
  if (qtile >= 21) return;
  int qb = qtile * 16;

  f16x8 qf = *(const f16x8*)&Q[base + (size_t)(qb + lcol) * DD + quad * 8];
  f32x4 accA = {0.f, 0.f, 0.f, 0.f};
  f32x4 accB = {0.f, 0.f, 0.f, 0.f};
  f32x4 lacc = {0.f, 0.f, 0.f, 0.f};
  float m_[4] = {-1e30f, -1e30f, -1e30f, -1e30f};
  _Float16* P = Ps[wave];
  const f16x8 onesv = {(_Float16)1.f, (_Float16)1.f, (_Float16)1.f, (_Float16)1.f,
                       (_Float16)1.f, (_Float16)1.f, (_Float16)1.f, (_Float16)1.f};
  const f32x4 z4 = {0.f, 0.f, 0.f, 0.f};

  for (int t = 0; t < 11; ++t) {
    int k0 = t * 32;
    bool full = (t < 10);
    const _Float16* kp0 = &Ks[(k0 + lcol) * KSTR + quad * 8];
    f16x4v ka = *(const f16x4v*)kp0;
    f16x4v kb = *(const f16x4v*)(kp0 + 4);
    f16x8 kf0 = __builtin_shufflevector(ka, kb, 0, 1, 2, 3, 4, 5, 6, 7);
    f32x4 s0 = __builtin_amdgcn_mfma_f32_16x16x32_f16(qf, kf0, z4, 0, 0, 0);
    f32x4 s1 = z4;
    if (full) {
      const _Float16* kp1 = &Ks[(k0 + 16 + lcol) * KSTR + quad * 8];
      f16x4v ka1 = *(const f16x4v*)kp1;
      f16x4v kb1 = *(const f16x4v*)(kp1 + 4);
      f16x8 kf1 = __builtin_shufflevector(ka1, kb1, 0, 1, 2, 3, 4, 5, 6, 7);
      s1 = __builtin_amdgcn_mfma_f32_16x16x32_f16(qf, kf1, z4, 0, 0, 0);
    }
    float sc0[4], sc1[4], p0[4], p1[4], corr[4];
#pragma unroll
    for (int i = 0; i < 4; ++i) {
      sc0[i] = s0[i] * ATT_SCALE;
      sc1[i] = full ? s1[i] * ATT_SCALE : -1e30f;
    }
#pragma unroll
    for (int i = 0; i < 4; ++i) {
      float t2 = fmaxf(sc0[i], sc1[i]);
      t2 = fmaxf(t2, __shfl_xor(t2, 1));
      t2 = fmaxf(t2, __shfl_xor(t2, 2));
      t2 = fmaxf(t2, __shfl_xor(t2, 4));
      t2 = fmaxf(t2, __shfl_xor(t2, 8));
      float nm = fmaxf(m_[i], t2);
      corr[i] = __expf(m_[i] - nm);
      m_[i] = nm;
      p0[i] = __expf(sc0[i] - nm);
      p1[i] = __expf(sc1[i] - nm);
      accA[i] *= corr[i];
      accB[i] *= corr[i];
      lacc[i] *= corr[i];
    }
#pragma unroll
    for (int i = 0; i < 4; ++i) {
      P[(quad * 4 + i) * 40 + lcol] = f2h(p0[i]);
      P[(quad * 4 + i) * 40 + 16 + lcol] = f2h(p1[i]);
    }
    f16x8 pf = *(const f16x8*)&P[lcol * 40 + quad * 8];
    lacc = __builtin_amdgcn_mfma_f32_16x16x32_f16(pf, onesv, lacc, 0, 0, 0);
    f16x8 vb0 = *(const f16x8*)&Vt[lcol * VTSTR + k0 + quad * 8];
    f16x8 vb1 = *(const f16x8*)&Vt[(16 + lcol) * VTSTR + k0 + quad * 8];
    accA = __builtin_amdgcn_mfma_f32_16x16x32_f16(pf, vb0, accA, 0, 0, 0);
    accB = __builtin_amdgcn_mfma_f32_16x16x32_f16(pf, vb1, accB, 0, 0, 0);
  }

#pragma unroll
  for (int i = 0; i < 4; ++i) {
    float inv = 1.f / lacc[i];
    P[(quad * 4 + i) * 40 + lcol] = f2h(accA[i] * inv);
    P[(quad * 4 + i) * 40 + 16 + lcol] = f2h(accB[i] * inv);
  }
  int row = lane >> 2, seg = lane & 3;
  f16x8 ov = *(const f16x8*)&P[row * 40 + seg * 8];
  *(f16x8*)&O16[base + (size_t)(qb + row) * DD + seg * 8] = ov;
}

// ---------------- MEGA var stage -------------------------------------------
// grid 168 x 256thr; block owns 32 var-layout rows (= 4 complete n-groups).
// Does: gather AO(time rows) -> O-proj+bias+res(Etime) -> LN1 -> LNnorm ->
// QKV -> attn(L=8) -> O-proj+bias+res -> LN1 -> permuted store to Etime/Et16.
// In-place Etime safe: block's var-rows <-> time-rows is a bijection.
__global__ __launch_bounds__(256) void k_mega_var(
    const _Float16* __restrict__ AO16, const _Float16* __restrict__ WT,
    const float* __restrict__ bq, const float* __restrict__ bk,
    const float* __restrict__ bv, const float* __restrict__ bo,
    const float* __restrict__ g1, const float* __restrict__ c1,
    const float* __restrict__ gn, const float* __restrict__ bn,
    float* __restrict__ Etime, _Float16* __restrict__ Et16) {
  int tid = threadIdx.x;
  int wave = tid >> 6, lane = tid & 63;
  int quad = lane >> 4, lcol = lane & 15;

  __shared__ int rmapS[32];
  __shared__ _Float16 Af[32 * 264];    // 16.5 KB: AO / x_var f16 / attn-out
  __shared__ float Cf[32 * 260];       // 33.3 KB: fp32 rows (LN workspace)
  __shared__ _Float16 QKVs[32 * 776];  // 48.5 KB

  if (tid < 32) {
    int r2 = blockIdx.x * 32 + tid;
    int n_idx = r2 >> 3, v = r2 & 7;
    int b = n_idx / SS, s = n_idx - b * SS;
    rmapS[tid] = (b * VV + v) * SS + s;
  }
  __syncthreads();

  // stage AO rows (time layout, gathered) into Af
  {
    int row = tid >> 3, seg = tid & 7;
    const _Float16* src = AO16 + (size_t)rmapS[row] * DD + seg * 32;
    _Float16* dst = Af + row * 264 + seg * 32;
#pragma unroll
    for (int j = 0; j < 4; ++j)
      *(f16x8*)(dst + j * 8) = *(const f16x8*)(src + j * 8);
  }
  __syncthreads();

  const _Float16* WoT = WT + 3 * 65536;

  // ---- time O-proj: Cf = Af @ Wo + bo + Etime(res) ----
  {
    f32x4 acc[2][4] = {};
    for (int k0 = 0; k0 < 256; k0 += 32) {
      f16x8 af0 = *(const f16x8*)&Af[(lcol)*264 + k0 + quad * 8];
      f16x8 af1 = *(const f16x8*)&Af[(16 + lcol) * 264 + k0 + quad * 8];
#pragma unroll
      for (int nt = 0; nt < 4; ++nt) {
        int n0 = wave * 64 + nt * 16;
        f16x8 bfr = *(const f16x8*)&WoT[(size_t)(n0 + lcol) * 256 + k0 + quad * 8];
        acc[0][nt] = __builtin_amdgcn_mfma_f32_16x16x32_f16(af0, bfr, acc[0][nt], 0, 0, 0);
        acc[1][nt] = __builtin_amdgcn_mfma_f32_16x16x32_f16(af1, bfr, acc[1][nt], 0, 0, 0);
      }
    }
#pragma unroll
    for (int mt = 0; mt < 2; ++mt)
#pragma unroll
      for (int i = 0; i < 4; ++i) {
        int row = mt * 16 + quad * 4 + i;
        size_t rb = (size_t)rmapS[row] * 256;
#pragma unroll
        for (int nt = 0; nt < 4; ++nt) {
          int col = wave * 64 + nt * 16 + lcol;
          Cf[row * 260 + col] = acc[mt][nt][i] + bo[col] + Etime[rb + col];
        }
      }
  }
  __syncthreads();

  // ---- double LN (ln1 then norm) on Cf rows; write Cf fp32 + Af f16 ----
  {
    int row = tid >> 3, c0 = (tid & 7) * 32;
    float v[32];
#pragma unroll
    for (int j = 0; j < 32; ++j) v[j] = Cf[row * 260 + c0 + j];
#pragma unroll
    for (int pass = 0; pass < 2; ++pass) {
      const float* gg = pass ? gn : g1;
      const float* bb = pass ? bn : c1;
      float s = 0.f, q = 0.f;
#pragma unroll
      for (int j = 0; j < 32; ++j) { s += v[j]; q = fmaf(v[j], v[j], q); }
      s += __shfl_xor(s, 1); q += __shfl_xor(q, 1);
      s += __shfl_xor(s, 2); q += __shfl_xor(q, 2);
      s += __shfl_xor(s, 4); q += __shfl_xor(q, 4);
      float mu = s * (1.0f / 256.0f);
      float rs = rsqrtf(q * (1.0f / 256.0f) - mu * mu + LN_EPS);
#pragma unroll
      for (int j = 0; j < 32; ++j)
        v[j] = fmaf((v[j] - mu) * rs, gg[c0 + j], bb[c0 + j]);
    }
#pragma unroll
    for (int j = 0; j < 32; ++j) Cf[row * 260 + c0 + j] = v[j];
#pragma unroll
    for (int j4 = 0; j4 < 4; ++j4) {
      f16x8 h;
#pragma unroll
      for (int jj = 0; jj < 8; ++jj) h[jj] = f2h(v[j4 * 8 + jj]);
      *(f16x8*)&Af[row * 264 + c0 + j4 * 8] = h;
    }
  }
  __syncthreads();

  // ---- QKV: QKVs[32][768] = Af @ {Wq|Wk|Wv} + bias ----
#pragma unroll
  for (int ch = 0; ch < 3; ++ch) {
    f32x4 acc[2][4] = {};
    for (int k0 = 0; k0 < 256; k0 += 32) {
      f16x8 af0 = *(const f16x8*)&Af[(lcol)*264 + k0 + quad * 8];
      f16x8 af1 = *(const f16x8*)&Af[(16 + lcol) * 264 + k0 + quad * 8];
#pragma unroll
      for (int nt = 0; nt < 4; ++nt) {
        int ntg = wave * 12 + ch * 4 + nt;       // 0..47
        int colb = ntg * 16;
        int z = colb >> 8, coln = colb & 255;
        f16x8 bfr = *(const f16x8*)&WT[(size_t)z * 65536 +
                                       (size_t)(coln + lcol) * 256 + k0 + quad * 8];
        acc[0][nt] = __builtin_amdgcn_mfma_f32_16x16x32_f16(af0, bfr, acc[0][nt], 0, 0, 0);
        acc[1][nt] = __builtin_amdgcn_mfma_f32_16x16x32_f16(af1, bfr, acc[1][nt], 0, 0, 0);
      }
    }
#pragma unroll
    for (int nt = 0; nt < 4; ++nt) {
      int ntg = wave * 12 + ch * 4 + nt;
      int colb = ntg * 16;
      int z = colb >> 8, coln = (colb & 255) + lcol;
      const float* bz = (z == 0) ? bq : (z == 1) ? bk : bv;
      float bval = bz[coln];
#pragma unroll
      for (int mt = 0; mt < 2; ++mt)
#pragma unroll
        for (int i = 0; i < 4; ++i)
          QKVs[(mt * 16 + quad * 4 + i) * 776 + colb + lcol] =
              f2h(acc[mt][nt][i] + bval);
    }
  }
  __syncthreads();

  // ---- var attention: 4 n-groups x 8 heads x 8 q ----
  {
    int ng = tid >> 6, h = (tid >> 3) & 7, qi = tid & 7;
    const _Float16* Qp = &QKVs[(ng * 8 + qi) * 776 + h * 32];
    float qv[32];
#pragma unroll
    for (int j4 = 0; j4 < 4; ++j4) {
      f16x8 t = *(const f16x8*)(Qp + j4 * 8);
#pragma unroll
      for (int jj = 0; jj < 8; ++jj) qv[j4 * 8 + jj] = (float)t[jj];
    }
    float sc[8];
#pragma unroll
    for (int k = 0; k < 8; ++k) {
      const _Float16* Kp = &QKVs[(ng * 8 + k) * 776 + 256 + h * 32];
      float s = 0.f;
#pragma unroll
      for (int j4 = 0; j4 < 4; ++j4) {
        f16x8 t = *(const f16x8*)(Kp + j4 * 8);
#pragma unroll
        for (int jj = 0; jj < 8; ++jj) s = fmaf(qv[j4 * 8 + jj], (float)t[jj], s);
      }
      sc[k] = s * ATT_SCALE;
    }
    float mx = sc[0];
#pragma unroll
    for (int k = 1; k < 8; ++k) mx = fmaxf(mx, sc[k]);
    float ps = 0.f;
#pragma unroll
    for (int k = 0; k < 8; ++k) { sc[k] = __expf(sc[k] - mx); ps += sc[k]; }
    float inv = 1.f / ps;
    float ov[32];
#pragma unroll
    for (int j = 0; j < 32; ++j) ov[j] = 0.f;
#pragma unroll
    for (int k = 0; k < 8; ++k) {
      const _Float16* Vp = &QKVs[(ng * 8 + k) * 776 + 512 + h * 32];
      float p = sc[k];
#pragma unroll
      for (int j4 = 0; j4 < 4; ++j4) {
        f16x8 t = *(const f16x8*)(Vp + j4 * 8);
#pragma unroll
        for (int jj = 0; jj < 8; ++jj)
          ov[j4 * 8 + jj] = fmaf(p, (float)t[jj], ov[j4 * 8 + jj]);
      }
    }
    _Float16* Op = &Af[(ng * 8 + qi) * 264 + h * 32];
#pragma unroll
    for (int j4 = 0; j4 < 4; ++j4) {
      f16x8 hh;
#pragma unroll
      for (int jj = 0; jj < 8; ++jj) hh[jj] = f2h(ov[j4 * 8 + jj] * inv);
      *(f16x8*)(Op + j4 * 8) = hh;
    }
  }
  __syncthreads();

  // ---- var O-proj: Cf = Af @ Wo + bo + Cf(res x_var) ----
  {
    f32x4 acc[2][4] = {};
    for (int k0 = 0; k0 < 256; k0 += 32) {
      f16x8 af0 = *(const f16x8*)&Af[(lcol)*264 + k0 + quad * 8];
      f16x8 af1 = *(const f16x8*)&Af[(16 + lcol) * 264 + k0 + quad * 8];
#pragma unroll
      for (int nt = 0; nt < 4; ++nt) {
        int n0 = wave * 64 + nt * 16;
        f16x8 bfr = *(const f16x8*)&WoT[(size_t)(n0 + lcol) * 256 + k0 + quad * 8];
        acc[0][nt] = __builtin_amdgcn_mfma_f32_16x16x32_f16(af0, bfr, acc[0][nt], 0, 0, 0);
        acc[1][nt] = __builtin_amdgcn_mfma_f32_16x16x32_f16(af1, bfr, acc[1][nt], 0, 0, 0);
      }
    }
#pragma unroll
    for (int mt = 0; mt < 2; ++mt)
#pragma unroll
      for (int i = 0; i < 4; ++i) {
        int row = mt * 16 + quad * 4 + i;
#pragma unroll
        for (int nt = 0; nt < 4; ++nt) {
          int col = wave * 64 + nt * 16 + lcol;
          // single-owner cell: read residual then overwrite, no race
          Cf[row * 260 + col] = acc[mt][nt][i] + bo[col] + Cf[row * 260 + col];
        }
      }
  }
  __syncthreads();

  // ---- final LN1 + permuted store (var -> time layout) ----
  {
    int row = tid >> 3, c0 = (tid & 7) * 32;
    float v[32];
#pragma unroll
    for (int j = 0; j < 32; ++j) v[j] = Cf[row * 260 + c0 + j];
    float s = 0.f, q = 0.f;
#pragma unroll
    for (int j = 0; j < 32; ++j) { s += v[j]; q = fmaf(v[j], v[j], q); }
    s += __shfl_xor(s, 1); q += __shfl_xor(q, 1);
    s += __shfl_xor(s, 2); q += __shfl_xor(q, 2);
    s += __shfl_xor(s, 4); q += __shfl_xor(q, 4);
    float mu = s * (1.0f / 256.0f);
    float rs = rsqrtf(q * (1.0f / 256.0f) - mu * mu + LN_EPS);
#pragma unroll
    for (int j = 0; j < 32; ++j)
      v[j] = fmaf((v[j] - mu) * rs, g1[c0 + j], c1[c0 + j]);
    size_t rb = (size_t)rmapS[row] * 256 + c0;
#pragma unroll
    for (int j4 = 0; j4 < 8; ++j4) {
      float4 f4 = make_float4(v[j4 * 4], v[j4 * 4 + 1], v[j4 * 4 + 2], v[j4 * 4 + 3]);
      *(float4*)&Etime[rb + j4 * 4] = f4;
    }
#pragma unroll
    for (int j4 = 0; j4 < 4; ++j4) {
      f16x8 hh;
#pragma unroll
      for (int jj = 0; jj < 8; ++jj) hh[jj] = f2h(v[j4 * 8 + jj]);
      *(f16x8*)&Et16[rb + j4 * 8] = hh;
    }
  }
}

// ---------------- final projection -----------------------------------------
__global__ __launch_bounds__(192) void k_proj_partial(
    const float* __restrict__ E, const float* __restrict__ PW,
    float* __restrict__ Part) {
  int kc = blockIdx.x;
  int tid = threadIdx.x;
  int p4 = tid % 24, g = tid / 24;
  __shared__ float Es[16][128];
  __shared__ float sm[8][1536];
  for (int idx = tid; idx < 512; idx += 192) {
    int row = idx >> 5, kk4 = idx & 31;
    *(float4*)&Es[row][kk4 * 4] =
        *(const float4*)&E[(size_t)row * 86016 + kc * 128 + kk4 * 4];
  }
  __syncthreads();
  float4 acc[16];
#pragma unroll
  for (int i = 0; i < 16; ++i) acc[i] = make_float4(0.f, 0.f, 0.f, 0.f);
  for (int j = 0; j < 16; ++j) {
    int k = g * 16 + j;
    float4 w = *(const float4*)&PW[(size_t)(kc * 128 + k) * 96 + p4 * 4];
#pragma unroll
    for (int row = 0; row < 16; ++row) {
      float e = Es[row][k];
      acc[row].x = fmaf(e, w.x, acc[row].x);
      acc[row].y = fmaf(e, w.y, acc[row].y);
      acc[row].z = fmaf(e, w.z, acc[row].z);
      acc[row].w = fmaf(e, w.w, acc[row].w);
    }
  }
#pragma unroll
  for (int row = 0; row < 16; ++row)
    *(float4*)&sm[g][row * 96 + p4 * 4] = acc[row];
  __syncthreads();
  for (int o = tid; o < 1536; o += 192) {
    float s = 0.f;
#pragma unroll
    for (int g2 = 0; g2 < 8; ++g2) s += sm[g2][o];
    Part[(size_t)kc * 1536 + o] = s;
  }
}

__global__ __launch_bounds__(256) void k_proj_reduce(
    const float* __restrict__ Part, const float* __restrict__ PB,
    float* __restrict__ out) {
  int j = blockIdx.x * 256 + threadIdx.x;   // 1536 = row*96 + p
  int row = j / 96, p = j - row * 96;
  float s = PB[p];
#pragma unroll 8
  for (int c = 0; c < 672; ++c) s += Part[(size_t)c * 1536 + j];
  int b = row >> 3, v = row & 7;
  out[b * 768 + p * 8 + v] = s;
}

// ---------------- launch ---------------------------------------------------
extern "C" void kernel_launch(void* const* d_in, const int* in_sizes, int n_in,
                              void* d_out, int out_size, void* d_ws,
                              size_t ws_size, hipStream_t stream) {
  const float* x     = (const float*)d_in[0];
  const float* emb_w = (const float*)d_in[1];
  const float* emb_b = (const float*)d_in[2];
  const float* Wq = (const float*)d_in[3];
  const float* bq = (const float*)d_in[4];
  const float* Wk = (const float*)d_in[5];
  const float* bk = (const float*)d_in[6];
  const float* Wv = (const float*)d_in[7];
  const float* bv = (const float*)d_in[8];
  const float* Wo = (const float*)d_in[9];
  const float* bo = (const float*)d_in[10];
  const float* g1 = (const float*)d_in[11];
  const float* b1 = (const float*)d_in[12];
  const float* gn = (const float*)d_in[13];
  const float* bn = (const float*)d_in[14];
  const float* PW = (const float*)d_in[15];
  const float* PB = (const float*)d_in[16];
  float* out = (float*)d_out;

  float* ws = (float*)d_ws;
  float* Etime   = ws;                              // NTD f32
  _Float16* Et16 = (_Float16*)(ws + (size_t)NTD);   // NTD f16
  _Float16* Q16  = (_Float16*)(ws + (size_t)NTD + NTD / 2);
  _Float16* K16  = Q16 + (size_t)NTD;
  _Float16* V16  = K16 + (size_t)NTD;
  _Float16* AO16 = V16 + (size_t)NTD;
  _Float16* WT   = AO16 + (size_t)NTD;              // 4*65536 f16
  float* Part    = (float*)(WT + 4 * 65536);        // 672*1536 f32

  k_prep_w<<<dim3(256, 4), 256, 0, stream>>>(Wq, Wk, Wv, Wo, WT);
  k_embed<<<NTOK, 256, 0, stream>>>(x, emb_w, emb_b, Etime, Et16);
  for (int it = 0; it < 10; ++it) {
    k_gemm_qkv<<<dim3(84, 2, 3), 256, 0, stream>>>(
        Et16, WT, WT + 65536, WT + 2 * 65536, bq, bk, bv, Q16, K16, V16);
    k_attn_time<<<dim3(6, 8, 16), 256, 0, stream>>>(Q16, K16, V16, AO16);
    k_mega_var<<<168, 256, 0, stream>>>(
        AO16, WT, bq, bk, bv, bo, g1, b1, gn, bn, Etime, Et16);
  }
  k_proj_partial<<<672, 192, 0, stream>>>(Etime, PW, Part);
  k_proj_reduce<<<6, 256, 0, stream>>>(Part, PB, out);
}